// Round 1
// 244.465 us; speedup vs baseline: 1.1861x; 1.1861x over previous
//
#include <hip/hip_runtime.h>

#define D_MODEL 1024
#define NUM_HEADS 16
#define SEQ 2048
#define BATCH 2

typedef __attribute__((ext_vector_type(8))) short bf16x8;
typedef __attribute__((ext_vector_type(4))) float f32x4;

__device__ __forceinline__ float bf2f(unsigned short u) {
    return __uint_as_float(((unsigned int)u) << 16);
}
__device__ __forceinline__ unsigned short f2bf(float f) {
    unsigned int u = __float_as_uint(f);
    return (unsigned short)((u + 0x7FFFu + ((u >> 16) & 1u)) >> 16);   // RTNE
}
__device__ __forceinline__ ushort4 pack4(float4 v) {
    return make_ushort4(f2bf(v.x), f2bf(v.y), f2bf(v.z), f2bf(v.w));
}

// async global->LDS, 16B per lane. LDS dest = wave-uniform base + lane*16.
__device__ __forceinline__ void gload_lds16(const unsigned short* g, unsigned short* l) {
    __builtin_amdgcn_global_load_lds(
        (const __attribute__((address_space(1))) unsigned int*)g,
        (__attribute__((address_space(3))) unsigned int*)l,
        16, 0, 0);
}

// Swizzled 16B read from a [64][64] bf16 LDS tile. chunk = 16B column index.
// Layout: LDS[row*128 + chunk*16] holds G[row][(chunk^(row&7))*16 ..] bytes,
// established by pre-swizzling the global source in the staging loads.
__device__ __forceinline__ bf16x8 lds_read_swz(const unsigned short (*tile)[64], int row, int chunk) {
    const char* p = reinterpret_cast<const char*>(tile);
    return *reinterpret_cast<const bf16x8*>(p + row * 128 + (((chunk ^ (row & 7))) << 4));
}

// fp32 -> bf16 bulk convert (one float4 -> ushort4 per thread).
__global__ __launch_bounds__(256) void conv_kernel(
    const float* __restrict__ src, unsigned short* __restrict__ dst, int n4)
{
    int i = blockIdx.x * 256 + threadIdx.x;
    if (i < n4) {
        float4 v = reinterpret_cast<const float4*>(src)[i];
        reinterpret_cast<ushort4*>(dst)[i] = pack4(v);
    }
}

// MFMA NT-GEMM: C[m,n] = sum_i x[m,i] * W[n,i]. x fp32, W bf16 (pre-converted).
// 128x128 tile, BK=32. 1D grid, XCD-swizzled: lin = b + 8*(which + 3*y).
// Q,K: RoPE fused, [b][h][s][d]. V: TRANSPOSED write [b][h][d][s].
__global__ __launch_bounds__(256) void qkv_mfma_kernel(
    const float* __restrict__ x,
    const unsigned short* __restrict__ w3,   // [3][1024][1024] bf16
    unsigned short* __restrict__ qb, unsigned short* __restrict__ kb,
    unsigned short* __restrict__ vt)
{
    const int lin = blockIdx.x;
    const int b = lin & 7;
    const int t = lin >> 3;
    const int which = t % 3;
    const int y = t / 3;
    const unsigned short* __restrict__ W = w3 + (size_t)which * 1048576;
    const int m0 = y * 128;
    const int n0g = b * 128;

    __shared__ __align__(16) unsigned short As[128][40];  // 80 B stride
    __shared__ __align__(16) unsigned short Bs[128][40];

    const int tid = threadIdx.x;
    const int w = tid >> 6;
    const int lane = tid & 63;
    const int quad = lane >> 4;
    const int c15 = lane & 15;
    const int qm = w >> 1, qn = w & 1;

    const int srow = tid >> 1;
    const int scol = (tid & 1) * 16;

    f32x4 acc[4][4];
#pragma unroll
    for (int mi = 0; mi < 4; mi++)
#pragma unroll
        for (int ni = 0; ni < 4; ni++) acc[mi][ni] = (f32x4){0.f, 0.f, 0.f, 0.f};

    for (int kb0 = 0; kb0 < 1024; kb0 += 32) {
        const float* ap = x + (size_t)(m0 + srow) * 1024 + kb0 + scol;
        float4 a0 = *reinterpret_cast<const float4*>(ap + 0);
        float4 a1 = *reinterpret_cast<const float4*>(ap + 4);
        float4 a2 = *reinterpret_cast<const float4*>(ap + 8);
        float4 a3 = *reinterpret_cast<const float4*>(ap + 12);
        const unsigned short* wp = W + (size_t)(n0g + srow) * 1024 + kb0 + scol;
        uint4 b0 = *reinterpret_cast<const uint4*>(wp);
        uint4 b1 = *reinterpret_cast<const uint4*>(wp + 8);

        __syncthreads();
        {
            ushort4* ad = reinterpret_cast<ushort4*>(&As[srow][scol]);
            ad[0] = pack4(a0); ad[1] = pack4(a1); ad[2] = pack4(a2); ad[3] = pack4(a3);
            uint4* bd = reinterpret_cast<uint4*>(&Bs[srow][scol]);
            bd[0] = b0; bd[1] = b1;
        }
        __syncthreads();

        bf16x8 af[4], bfr[4];
#pragma unroll
        for (int mi = 0; mi < 4; mi++)
            af[mi] = *reinterpret_cast<const bf16x8*>(&As[qm * 64 + mi * 16 + c15][quad * 8]);
#pragma unroll
        for (int ni = 0; ni < 4; ni++)
            bfr[ni] = *reinterpret_cast<const bf16x8*>(&Bs[qn * 64 + ni * 16 + c15][quad * 8]);
#pragma unroll
        for (int mi = 0; mi < 4; mi++)
#pragma unroll
            for (int ni = 0; ni < 4; ni++)
                acc[mi][ni] = __builtin_amdgcn_mfma_f32_16x16x32_bf16(af[mi], bfr[ni], acc[mi][ni], 0, 0, 0);
    }

    // Epilogue: RoPE (Q,K) in registers -> wave-private LDS stage -> coalesced
    // stores. Wave's n-range = one head: h = b*2 + qn.
    __syncthreads();
    unsigned short* stg = &As[0][0] + w * (16 * 72);   // 16 rows x 72 stride, per wave
    const int hq = b * 2 + qn;
    unsigned short* outp = (which == 0) ? qb : kb;

    float invf[4];
#pragma unroll
    for (int ni = 0; ni < 4; ni++)
        invf[ni] = powf(10000.0f, -((float)(((ni * 16 + c15) & 63) >> 1)) / 32.0f);
    const int odd = c15 & 1;

#pragma unroll
    for (int mi = 0; mi < 4; mi++) {
#pragma unroll
        for (int r = 0; r < 4; r++) {
            int m = m0 + qm * 64 + mi * 16 + quad * 4 + r;
            int s = m & (SEQ - 1);
#pragma unroll
            for (int ni = 0; ni < 4; ni++) {
                float val = acc[mi][ni][r];
                float res;
                if (which < 2) {
                    float part = __shfl_xor(val, 1);
                    float sn, cs;
                    sincosf((float)s * invf[ni], &sn, &cs);
                    res = odd ? (part * sn + val * cs) : (val * cs - part * sn);
                } else {
                    res = val;
                }
                stg[(quad * 4 + r) * 72 + ni * 16 + c15] = f2bf(res);
            }
        }
        if (which < 2) {
            // rows of [s][d]: 4 lanes per row, 32 B each -> 128 B contiguous
            int row = lane >> 2;
            int ch = lane & 3;
            int m = m0 + qm * 64 + mi * 16 + row;
            int s = m & (SEQ - 1);
            int bb = m >> 11;
            size_t ob = (((size_t)bb * NUM_HEADS + hq) * SEQ + s) * 64 + ch * 16;
            uint4 v0 = *reinterpret_cast<const uint4*>(&stg[row * 72 + ch * 16]);
            uint4 v1 = *reinterpret_cast<const uint4*>(&stg[row * 72 + ch * 16 + 8]);
            *reinterpret_cast<uint4*>(&outp[ob]) = v0;
            *reinterpret_cast<uint4*>(&outp[ob + 8]) = v1;
        } else {
            // transposed write to vt[b][h][d][s]: lane = d, 16 s values = 32 B
            int mbase = m0 + qm * 64 + mi * 16;
            int bb = mbase >> 11;
            int s_base = mbase & (SEQ - 1);
            unsigned short tmp[16];
#pragma unroll
            for (int sl = 0; sl < 16; sl++) tmp[sl] = stg[sl * 72 + lane];
            size_t ob = (((size_t)bb * NUM_HEADS + hq) * 64 + lane) * SEQ + s_base;
            *reinterpret_cast<uint4*>(&vt[ob])     = *reinterpret_cast<uint4*>(&tmp[0]);
            *reinterpret_cast<uint4*>(&vt[ob + 8]) = *reinterpret_cast<uint4*>(&tmp[8]);
        }
    }
}

// MFMA flash attention. Block (x, bh) processes Q-tiles {31-x, x} sequentially
// (perfect balance: 33 tile-iterations per block). K,V tiles are staged into
// LDS via global_load_lds (coalesced, issued once per block instead of 4x per
// wave), double-buffered one iteration ahead: the single per-iteration barrier
// drains vmcnt with a full iteration of compute as cover. LDS layout uses the
// linear-dest + pre-swizzled-source + swizzled-read XOR pattern so ds_read_b128
// fragment reads are bank-conflict-free.
__global__ __launch_bounds__(256) void attn_kernel(
    const unsigned short* __restrict__ qb, const unsigned short* __restrict__ kb,
    const unsigned short* __restrict__ vt, unsigned short* __restrict__ ab)
{
    const int xpair = blockIdx.x;   // 0..15
    const int bh = blockIdx.y;
    const int b = bh >> 4, h = bh & 15;
    const size_t base = (size_t)bh * SEQ * 64;     // qb/kb [b][h][s][d]
    const size_t vbase = (size_t)bh * 64 * SEQ;    // vt [b][h][d][s]
    const int tid = threadIdx.x;
    const int w = tid >> 6;
    const int lane = tid & 63;
    const int quad = lane >> 4;
    const int c15 = lane & 15;
    const int srow8 = lane >> 3;   // row within a 8-row staging instruction
    const int sch = lane & 7;      // 16B chunk within a 128B row

    __shared__ __align__(16) unsigned short Ks[2][64][64];   // [buf][j][d]
    __shared__ __align__(16) unsigned short Vs[2][64][64];   // [buf][d][j]
    __shared__ __align__(16) unsigned short Pl[64][72];      // wave-private rows

    // Stage K/V tile jts into buffer buf. Wave w covers rows [w*16, w*16+16):
    // 2 instructions of 8 rows x 128B each, linear LDS dest, source chunk
    // pre-swizzled so swizzled ds_read recovers the logical layout.
    auto stage = [&](int jts, int buf) {
        const int j0s = jts * 64;
#pragma unroll
        for (int i = 0; i < 2; i++) {
            const int row = w * 16 + i * 8 + srow8;
            const int ch = sch ^ (row & 7);
            gload_lds16(kb + base + (size_t)(j0s + row) * 64 + ch * 8,
                        &Ks[buf][w * 16 + i * 8][0]);
            gload_lds16(vt + vbase + (size_t)row * SEQ + j0s + ch * 8,
                        &Vs[buf][w * 16 + i * 8][0]);
        }
    };

    for (int pass = 0; pass < 2; pass++) {
        const int it = pass ? xpair : (31 - xpair);   // heavy tile first
        const int i0 = it * 64;

        const int qrow = i0 + w * 16 + c15;
        bf16x8 qf0 = *reinterpret_cast<const bf16x8*>(&qb[base + (size_t)qrow * 64 + quad * 8]);
        bf16x8 qf1 = *reinterpret_cast<const bf16x8*>(&qb[base + (size_t)qrow * 64 + 32 + quad * 8]);

        float m_st[4], l_st[4];
        f32x4 Oc[4];
#pragma unroll
        for (int r = 0; r < 4; r++) { m_st[r] = -1e30f; l_st[r] = 0.f; }
#pragma unroll
        for (int t = 0; t < 4; t++) Oc[t] = (f32x4){0.f, 0.f, 0.f, 0.f};

        __syncthreads();          // prev pass done reading buffers
        stage(0, 0);              // prologue: tile 0 -> buf 0

        for (int jt = 0; jt <= it; jt++) {
            const int j0 = jt * 64;
            const int cb = jt & 1;

            __syncthreads();      // staging for cb complete; nb free to overwrite
            if (jt < it) stage(jt + 1, cb ^ 1);

            // K fragments from LDS (swizzled, conflict-free)
            bf16x8 kc0[4], kc1[4];
#pragma unroll
            for (int t = 0; t < 4; t++) {
                kc0[t] = lds_read_swz(Ks[cb], t * 16 + c15, quad);
                kc1[t] = lds_read_swz(Ks[cb], t * 16 + c15, 4 + quad);
            }

            f32x4 sc[4];
#pragma unroll
            for (int t = 0; t < 4; t++) sc[t] = (f32x4){0.f, 0.f, 0.f, 0.f};
#pragma unroll
            for (int t = 0; t < 4; t++) {
                sc[t] = __builtin_amdgcn_mfma_f32_16x16x32_bf16(qf0, kc0[t], sc[t], 0, 0, 0);
                sc[t] = __builtin_amdgcn_mfma_f32_16x16x32_bf16(qf1, kc1[t], sc[t], 0, 0, 0);
            }

            // V fragments issued early so ds_read latency hides under softmax
            bf16x8 vv0[4], vv1[4];
#pragma unroll
            for (int t = 0; t < 4; t++) {
                vv0[t] = lds_read_swz(Vs[cb], t * 16 + c15, quad);
                vv1[t] = lds_read_swz(Vs[cb], t * 16 + c15, 4 + quad);
            }

#pragma unroll
            for (int t = 0; t < 4; t++)
#pragma unroll
                for (int r = 0; r < 4; r++) sc[t][r] *= 0.125f;
            if (jt == it) {
#pragma unroll
                for (int t = 0; t < 4; t++) {
                    int gj = j0 + t * 16 + c15;
#pragma unroll
                    for (int r = 0; r < 4; r++) {
                        int gi = i0 + w * 16 + quad * 4 + r;
                        if (gj > gi) sc[t][r] = -1e30f;
                    }
                }
            }

            float mnew[4], alpha[4], rsum[4];
#pragma unroll
            for (int r = 0; r < 4; r++) {
                float tm = fmaxf(fmaxf(sc[0][r], sc[1][r]), fmaxf(sc[2][r], sc[3][r]));
                tm = fmaxf(tm, __shfl_xor(tm, 1));
                tm = fmaxf(tm, __shfl_xor(tm, 2));
                tm = fmaxf(tm, __shfl_xor(tm, 4));
                tm = fmaxf(tm, __shfl_xor(tm, 8));
                mnew[r] = fmaxf(m_st[r], tm);
                alpha[r] = __expf(m_st[r] - mnew[r]);
                rsum[r] = 0.f;
            }
#pragma unroll
            for (int t = 0; t < 4; t++) {
#pragma unroll
                for (int r = 0; r < 4; r++) {
                    float p = __expf(sc[t][r] - mnew[r]);
                    rsum[r] += p;
                    Pl[w * 16 + quad * 4 + r][t * 16 + c15] = f2bf(p);
                }
            }
#pragma unroll
            for (int r = 0; r < 4; r++) {
                float s = rsum[r];
                s += __shfl_xor(s, 1);
                s += __shfl_xor(s, 2);
                s += __shfl_xor(s, 4);
                s += __shfl_xor(s, 8);
                l_st[r] = l_st[r] * alpha[r] + s;
                m_st[r] = mnew[r];
#pragma unroll
                for (int t = 0; t < 4; t++) Oc[t][r] *= alpha[r];
            }

            bf16x8 ap0 = *reinterpret_cast<const bf16x8*>(&Pl[w * 16 + c15][quad * 8]);
            bf16x8 ap1 = *reinterpret_cast<const bf16x8*>(&Pl[w * 16 + c15][32 + quad * 8]);
#pragma unroll
            for (int t = 0; t < 4; t++) {
                Oc[t] = __builtin_amdgcn_mfma_f32_16x16x32_bf16(ap0, vv0[t], Oc[t], 0, 0, 0);
                Oc[t] = __builtin_amdgcn_mfma_f32_16x16x32_bf16(ap1, vv1[t], Oc[t], 0, 0, 0);
            }
        }

        // Epilogue: stage O into Pl, coalesced uint4 stores.
#pragma unroll
        for (int r = 0; r < 4; r++) {
            float inv = 1.0f / l_st[r];
#pragma unroll
            for (int t = 0; t < 4; t++)
                Pl[w * 16 + quad * 4 + r][t * 16 + c15] = f2bf(Oc[t][r] * inv);
        }
        {
            int row = lane >> 2;
            int ch = lane & 3;
            int gi = i0 + w * 16 + row;
            size_t ob = ((size_t)b * SEQ + gi) * 1024 + h * 64 + ch * 16;
            uint4 v0 = *reinterpret_cast<const uint4*>(&Pl[w * 16 + row][ch * 16]);
            uint4 v1 = *reinterpret_cast<const uint4*>(&Pl[w * 16 + row][ch * 16 + 8]);
            *reinterpret_cast<uint4*>(&ab[ob]) = v0;
            *reinterpret_cast<uint4*>(&ab[ob + 8]) = v1;
        }
    }
}

// MFMA NT-GEMM: out[m,n] = sum_i ab[m,i] * Wo[n,i]; both bf16, out fp32.
__global__ __launch_bounds__(256) void out_mfma_kernel(
    const unsigned short* __restrict__ A, const unsigned short* __restrict__ Wob,
    float* __restrict__ out)
{
    const int lin = blockIdx.x;
    const int b = lin & 7;
    const int y = lin >> 3;
    const int m0 = y * 128;
    const int n0g = b * 128;

    __shared__ __align__(16) unsigned short As[128][40];
    __shared__ __align__(16) unsigned short Bs[128][40];

    const int tid = threadIdx.x;
    const int w = tid >> 6;
    const int lane = tid & 63;
    const int quad = lane >> 4;
    const int c15 = lane & 15;
    const int qm = w >> 1, qn = w & 1;

    const int srow = tid >> 1;
    const int scol = (tid & 1) * 16;

    f32x4 acc[4][4];
#pragma unroll
    for (int mi = 0; mi < 4; mi++)
#pragma unroll
        for (int ni = 0; ni < 4; ni++) acc[mi][ni] = (f32x4){0.f, 0.f, 0.f, 0.f};

    for (int kb0 = 0; kb0 < 1024; kb0 += 32) {
        const unsigned short* ap = A + (size_t)(m0 + srow) * 1024 + kb0 + scol;
        uint4 a0 = *reinterpret_cast<const uint4*>(ap);
        uint4 a1 = *reinterpret_cast<const uint4*>(ap + 8);
        const unsigned short* wp = Wob + (size_t)(n0g + srow) * 1024 + kb0 + scol;
        uint4 b0 = *reinterpret_cast<const uint4*>(wp);
        uint4 b1 = *reinterpret_cast<const uint4*>(wp + 8);

        __syncthreads();
        {
            uint4* ad = reinterpret_cast<uint4*>(&As[srow][scol]);
            ad[0] = a0; ad[1] = a1;
            uint4* bd = reinterpret_cast<uint4*>(&Bs[srow][scol]);
            bd[0] = b0; bd[1] = b1;
        }
        __syncthreads();

        bf16x8 af[4], bfr[4];
#pragma unroll
        for (int mi = 0; mi < 4; mi++)
            af[mi] = *reinterpret_cast<const bf16x8*>(&As[qm * 64 + mi * 16 + c15][quad * 8]);
#pragma unroll
        for (int ni = 0; ni < 4; ni++)
            bfr[ni] = *reinterpret_cast<const bf16x8*>(&Bs[qn * 64 + ni * 16 + c15][quad * 8]);
#pragma unroll
        for (int mi = 0; mi < 4; mi++)
#pragma unroll
            for (int ni = 0; ni < 4; ni++)
                acc[mi][ni] = __builtin_amdgcn_mfma_f32_16x16x32_bf16(af[mi], bfr[ni], acc[mi][ni], 0, 0, 0);
    }

#pragma unroll
    for (int mi = 0; mi < 4; mi++) {
#pragma unroll
        for (int r = 0; r < 4; r++) {
            int m = m0 + qm * 64 + mi * 16 + quad * 4 + r;
#pragma unroll
            for (int ni = 0; ni < 4; ni++) {
                int n = n0g + qn * 64 + ni * 16 + c15;
                out[(size_t)m * 1024 + n] = acc[mi][ni][r];
            }
        }
    }
}

extern "C" void kernel_launch(void* const* d_in, const int* in_sizes, int n_in,
                              void* d_out, int out_size, void* d_ws, size_t ws_size,
                              hipStream_t stream)
{
    const float* x  = (const float*)d_in[0];
    const float* Wq = (const float*)d_in[1];
    const float* Wk = (const float*)d_in[2];
    const float* Wv = (const float*)d_in[3];
    const float* Wo = (const float*)d_in[4];
    float* out = (float*)d_out;

    const size_t QKV_ELEMS = (size_t)BATCH * SEQ * D_MODEL;  // 4194304

    unsigned short* qb = (unsigned short*)d_ws;
    unsigned short* kb = qb + QKV_ELEMS;
    unsigned short* vt = kb + QKV_ELEMS;   // [b][h][d][s]
    unsigned short* ab = vt + QKV_ELEMS;
    unsigned short* w3bf = ab;             // dead during qkv
    unsigned short* wobf = qb;             // dead during out

    conv_kernel<<<dim3(3072), 256, 0, stream>>>(Wq, w3bf, 262144);
    conv_kernel<<<dim3(3072), 256, 0, stream>>>(Wk, w3bf + 1048576, 262144);
    conv_kernel<<<dim3(3072), 256, 0, stream>>>(Wv, w3bf + 2097152, 262144);
    qkv_mfma_kernel<<<dim3(768), 256, 0, stream>>>(x, w3bf, qb, kb, vt);
    attn_kernel<<<dim3(16, 32), 256, 0, stream>>>(qb, kb, vt, ab);
    conv_kernel<<<dim3(1024), 256, 0, stream>>>(Wo, wobf, 262144);
    out_mfma_kernel<<<dim3(256), 256, 0, stream>>>(ab, wobf, out);
}

// Round 2
// 237.684 us; speedup vs baseline: 1.2199x; 1.0285x over previous
//
#include <hip/hip_runtime.h>

#define D_MODEL 1024
#define NUM_HEADS 16
#define SEQ 2048
#define BATCH 2

typedef __attribute__((ext_vector_type(8))) short bf16x8;
typedef __attribute__((ext_vector_type(4))) float f32x4;

__device__ __forceinline__ float bf2f(unsigned short u) {
    return __uint_as_float(((unsigned int)u) << 16);
}
__device__ __forceinline__ unsigned short f2bf(float f) {
    unsigned int u = __float_as_uint(f);
    return (unsigned short)((u + 0x7FFFu + ((u >> 16) & 1u)) >> 16);   // RTNE
}
__device__ __forceinline__ ushort4 pack4(float4 v) {
    return make_ushort4(f2bf(v.x), f2bf(v.y), f2bf(v.z), f2bf(v.w));
}

// async global->LDS, 16B per lane. LDS dest = wave-uniform base + lane*16.
__device__ __forceinline__ void gload_lds16(const unsigned short* g, unsigned short* l) {
    __builtin_amdgcn_global_load_lds(
        (const __attribute__((address_space(1))) unsigned int*)g,
        (__attribute__((address_space(3))) unsigned int*)l,
        16, 0, 0);
}

// Swizzled 16B read from a [N][64] bf16 LDS tile (128B rows, 8 chunks).
// LDS[row][chunk] holds G[row][chunk ^ (row&7)] (established by pre-swizzling
// the global source in the staging loads), so reading chunk^(row&7) recovers
// the logical element and is bank-conflict-free (2-way) across 16 rows.
__device__ __forceinline__ bf16x8 lds_read_swz(const unsigned short (*tile)[64], int row, int chunk) {
    const char* p = reinterpret_cast<const char*>(tile);
    return *reinterpret_cast<const bf16x8*>(p + row * 128 + (((chunk ^ (row & 7))) << 4));
}

// fp32 -> bf16 bulk convert (one float4 -> ushort4 per thread).
__global__ __launch_bounds__(256) void conv_kernel(
    const float* __restrict__ src, unsigned short* __restrict__ dst, int n4)
{
    int i = blockIdx.x * 256 + threadIdx.x;
    if (i < n4) {
        float4 v = reinterpret_cast<const float4*>(src)[i];
        reinterpret_cast<ushort4*>(dst)[i] = pack4(v);
    }
}

// Fused conversion of x (1048576 float4) + Wq/Wk/Wv (262144 float4 each).
// One launch instead of four.
__global__ __launch_bounds__(256) void conv4_kernel(
    const float* __restrict__ x, const float* __restrict__ Wq,
    const float* __restrict__ Wk, const float* __restrict__ Wv,
    unsigned short* __restrict__ xb, unsigned short* __restrict__ w3bf)
{
    int i = blockIdx.x * 256 + threadIdx.x;
    const float* src;
    unsigned short* dst;
    int off;
    if (i < 1048576) {
        src = x; dst = xb; off = i;
    } else {
        int j = i - 1048576;
        int which = j >> 18;            // 262144 = 2^18
        off = j & 0x3FFFF;
        src = (which == 0) ? Wq : (which == 1) ? Wk : Wv;
        dst = w3bf + ((size_t)which << 20);   // 1048576 ushorts per W
        off = off;
    }
    float4 v = reinterpret_cast<const float4*>(src)[off];
    reinterpret_cast<ushort4*>(dst)[off] = pack4(v);
}

// MFMA NT-GEMM: C[m,n] = sum_i xb[m,i] * W[n,i], all bf16.
// 128x128 tile, BK=64, double-buffered global_load_lds staging with the
// inverse-swizzled-source + swizzled-read XOR layout (conflict-free ds_read).
// 1D grid, XCD-swizzled: lin = b + 8*(which + 3*y).
// Q,K: RoPE fused, [b][h][s][d]. V: TRANSPOSED write [b][h][d][s].
__global__ __launch_bounds__(256) void qkv_mfma_kernel(
    const unsigned short* __restrict__ xb,   // [4096][1024] bf16
    const unsigned short* __restrict__ w3,   // [3][1024][1024] bf16
    unsigned short* __restrict__ qb, unsigned short* __restrict__ kb,
    unsigned short* __restrict__ vt)
{
    const int lin = blockIdx.x;
    const int b = lin & 7;
    const int t = lin >> 3;
    const int which = t % 3;
    const int y = t / 3;
    const unsigned short* __restrict__ W = w3 + (size_t)which * 1048576;
    const int m0 = y * 128;
    const int n0g = b * 128;

    __shared__ __align__(16) unsigned short As[2][128][64];  // 32 KB
    __shared__ __align__(16) unsigned short Bs[2][128][64];  // 32 KB

    const int tid = threadIdx.x;
    const int w = tid >> 6;
    const int lane = tid & 63;
    const int quad = lane >> 4;
    const int c15 = lane & 15;
    const int qm = w >> 1, qn = w & 1;
    const int srow8 = lane >> 3;   // row within an 8-row staging instruction
    const int sch = lane & 7;      // 16B chunk within a 128B row

    // Stage one BK=64 K-slab of A and B into buffer buf.
    auto stage = [&](int k0, int buf) {
#pragma unroll
        for (int i = 0; i < 4; i++) {
            const int row = i * 32 + w * 8 + srow8;
            const int ch = sch ^ (row & 7);
            gload_lds16(xb + (size_t)(m0 + row) * 1024 + k0 + ch * 8,
                        &As[buf][i * 32 + w * 8][0]);
            gload_lds16(W + (size_t)(n0g + row) * 1024 + k0 + ch * 8,
                        &Bs[buf][i * 32 + w * 8][0]);
        }
    };

    f32x4 acc[4][4];
#pragma unroll
    for (int mi = 0; mi < 4; mi++)
#pragma unroll
        for (int ni = 0; ni < 4; ni++) acc[mi][ni] = (f32x4){0.f, 0.f, 0.f, 0.f};

    stage(0, 0);
    for (int k0 = 0; k0 < 1024; k0 += 64) {
        const int cb = (k0 >> 6) & 1;
        __syncthreads();                       // staging of cb complete
        if (k0 < 960) stage(k0 + 64, cb ^ 1);  // prefetch; drains at next barrier

        bf16x8 af[2][4], bfr[2][4];
#pragma unroll
        for (int ks = 0; ks < 2; ks++) {
#pragma unroll
            for (int mi = 0; mi < 4; mi++)
                af[ks][mi] = lds_read_swz(As[cb], qm * 64 + mi * 16 + c15, ks * 4 + quad);
#pragma unroll
            for (int ni = 0; ni < 4; ni++)
                bfr[ks][ni] = lds_read_swz(Bs[cb], qn * 64 + ni * 16 + c15, ks * 4 + quad);
        }
#pragma unroll
        for (int ks = 0; ks < 2; ks++)
#pragma unroll
            for (int mi = 0; mi < 4; mi++)
#pragma unroll
                for (int ni = 0; ni < 4; ni++)
                    acc[mi][ni] = __builtin_amdgcn_mfma_f32_16x16x32_bf16(af[ks][mi], bfr[ks][ni], acc[mi][ni], 0, 0, 0);
    }

    // Epilogue: RoPE (Q,K) in registers -> wave-private LDS stage -> coalesced
    // stores. Wave's n-range = one head: h = b*2 + qn.
    __syncthreads();
    unsigned short* stg = &As[0][0][0] + w * (16 * 72);   // 16 rows x 72 stride, per wave
    const int hq = b * 2 + qn;
    unsigned short* outp = (which == 0) ? qb : kb;

    float invf[4];
#pragma unroll
    for (int ni = 0; ni < 4; ni++)
        invf[ni] = powf(10000.0f, -((float)(((ni * 16 + c15) & 63) >> 1)) / 32.0f);
    const int odd = c15 & 1;

#pragma unroll
    for (int mi = 0; mi < 4; mi++) {
#pragma unroll
        for (int r = 0; r < 4; r++) {
            int m = m0 + qm * 64 + mi * 16 + quad * 4 + r;
            int s = m & (SEQ - 1);
#pragma unroll
            for (int ni = 0; ni < 4; ni++) {
                float val = acc[mi][ni][r];
                float res;
                if (which < 2) {
                    float part = __shfl_xor(val, 1);
                    float sn, cs;
                    sincosf((float)s * invf[ni], &sn, &cs);
                    res = odd ? (part * sn + val * cs) : (val * cs - part * sn);
                } else {
                    res = val;
                }
                stg[(quad * 4 + r) * 72 + ni * 16 + c15] = f2bf(res);
            }
        }
        if (which < 2) {
            // rows of [s][d]: 4 lanes per row, 32 B each -> 128 B contiguous
            int row = lane >> 2;
            int ch = lane & 3;
            int m = m0 + qm * 64 + mi * 16 + row;
            int s = m & (SEQ - 1);
            int bb = m >> 11;
            size_t ob = (((size_t)bb * NUM_HEADS + hq) * SEQ + s) * 64 + ch * 16;
            uint4 v0 = *reinterpret_cast<const uint4*>(&stg[row * 72 + ch * 16]);
            uint4 v1 = *reinterpret_cast<const uint4*>(&stg[row * 72 + ch * 16 + 8]);
            *reinterpret_cast<uint4*>(&outp[ob]) = v0;
            *reinterpret_cast<uint4*>(&outp[ob + 8]) = v1;
        } else {
            // transposed write to vt[b][h][d][s]: lane = d, 16 s values = 32 B
            int mbase = m0 + qm * 64 + mi * 16;
            int bb = mbase >> 11;
            int s_base = mbase & (SEQ - 1);
            unsigned short tmp[16];
#pragma unroll
            for (int sl = 0; sl < 16; sl++) tmp[sl] = stg[sl * 72 + lane];
            size_t ob = (((size_t)bb * NUM_HEADS + hq) * 64 + lane) * SEQ + s_base;
            *reinterpret_cast<uint4*>(&vt[ob])     = *reinterpret_cast<uint4*>(&tmp[0]);
            *reinterpret_cast<uint4*>(&vt[ob + 8]) = *reinterpret_cast<uint4*>(&tmp[8]);
        }
    }
}

// MFMA flash attention. Block (x, bh) processes Q-tiles {31-x, x} sequentially
// (perfect balance: 33 tile-iterations per block). K,V tiles staged into LDS
// via global_load_lds, double-buffered one iteration ahead; XOR-swizzled
// layout gives conflict-free ds_read_b128 fragment reads.
__global__ __launch_bounds__(256) void attn_kernel(
    const unsigned short* __restrict__ qb, const unsigned short* __restrict__ kb,
    const unsigned short* __restrict__ vt, unsigned short* __restrict__ ab)
{
    const int xpair = blockIdx.x;   // 0..15
    const int bh = blockIdx.y;
    const int b = bh >> 4, h = bh & 15;
    const size_t base = (size_t)bh * SEQ * 64;     // qb/kb [b][h][s][d]
    const size_t vbase = (size_t)bh * 64 * SEQ;    // vt [b][h][d][s]
    const int tid = threadIdx.x;
    const int w = tid >> 6;
    const int lane = tid & 63;
    const int quad = lane >> 4;
    const int c15 = lane & 15;
    const int srow8 = lane >> 3;
    const int sch = lane & 7;

    __shared__ __align__(16) unsigned short Ks[2][64][64];   // [buf][j][d]
    __shared__ __align__(16) unsigned short Vs[2][64][64];   // [buf][d][j]
    __shared__ __align__(16) unsigned short Pl[64][72];      // wave-private rows

    auto stage = [&](int jts, int buf) {
        const int j0s = jts * 64;
#pragma unroll
        for (int i = 0; i < 2; i++) {
            const int row = w * 16 + i * 8 + srow8;
            const int ch = sch ^ (row & 7);
            gload_lds16(kb + base + (size_t)(j0s + row) * 64 + ch * 8,
                        &Ks[buf][w * 16 + i * 8][0]);
            gload_lds16(vt + vbase + (size_t)row * SEQ + j0s + ch * 8,
                        &Vs[buf][w * 16 + i * 8][0]);
        }
    };

    for (int pass = 0; pass < 2; pass++) {
        const int it = pass ? xpair : (31 - xpair);   // heavy tile first
        const int i0 = it * 64;

        const int qrow = i0 + w * 16 + c15;
        bf16x8 qf0 = *reinterpret_cast<const bf16x8*>(&qb[base + (size_t)qrow * 64 + quad * 8]);
        bf16x8 qf1 = *reinterpret_cast<const bf16x8*>(&qb[base + (size_t)qrow * 64 + 32 + quad * 8]);

        float m_st[4], l_st[4];
        f32x4 Oc[4];
#pragma unroll
        for (int r = 0; r < 4; r++) { m_st[r] = -1e30f; l_st[r] = 0.f; }
#pragma unroll
        for (int t = 0; t < 4; t++) Oc[t] = (f32x4){0.f, 0.f, 0.f, 0.f};

        __syncthreads();          // prev pass done reading buffers
        stage(0, 0);              // prologue: tile 0 -> buf 0

        for (int jt = 0; jt <= it; jt++) {
            const int j0 = jt * 64;
            const int cb = jt & 1;

            __syncthreads();      // staging for cb complete; nb free to overwrite
            if (jt < it) stage(jt + 1, cb ^ 1);

            bf16x8 kc0[4], kc1[4];
#pragma unroll
            for (int t = 0; t < 4; t++) {
                kc0[t] = lds_read_swz(Ks[cb], t * 16 + c15, quad);
                kc1[t] = lds_read_swz(Ks[cb], t * 16 + c15, 4 + quad);
            }

            f32x4 sc[4];
#pragma unroll
            for (int t = 0; t < 4; t++) sc[t] = (f32x4){0.f, 0.f, 0.f, 0.f};
#pragma unroll
            for (int t = 0; t < 4; t++) {
                sc[t] = __builtin_amdgcn_mfma_f32_16x16x32_bf16(qf0, kc0[t], sc[t], 0, 0, 0);
                sc[t] = __builtin_amdgcn_mfma_f32_16x16x32_bf16(qf1, kc1[t], sc[t], 0, 0, 0);
            }

            bf16x8 vv0[4], vv1[4];
#pragma unroll
            for (int t = 0; t < 4; t++) {
                vv0[t] = lds_read_swz(Vs[cb], t * 16 + c15, quad);
                vv1[t] = lds_read_swz(Vs[cb], t * 16 + c15, 4 + quad);
            }

#pragma unroll
            for (int t = 0; t < 4; t++)
#pragma unroll
                for (int r = 0; r < 4; r++) sc[t][r] *= 0.125f;
            if (jt == it) {
#pragma unroll
                for (int t = 0; t < 4; t++) {
                    int gj = j0 + t * 16 + c15;
#pragma unroll
                    for (int r = 0; r < 4; r++) {
                        int gi = i0 + w * 16 + quad * 4 + r;
                        if (gj > gi) sc[t][r] = -1e30f;
                    }
                }
            }

            float mnew[4], alpha[4], rsum[4];
#pragma unroll
            for (int r = 0; r < 4; r++) {
                float tm = fmaxf(fmaxf(sc[0][r], sc[1][r]), fmaxf(sc[2][r], sc[3][r]));
                tm = fmaxf(tm, __shfl_xor(tm, 1));
                tm = fmaxf(tm, __shfl_xor(tm, 2));
                tm = fmaxf(tm, __shfl_xor(tm, 4));
                tm = fmaxf(tm, __shfl_xor(tm, 8));
                mnew[r] = fmaxf(m_st[r], tm);
                alpha[r] = __expf(m_st[r] - mnew[r]);
                rsum[r] = 0.f;
            }
#pragma unroll
            for (int t = 0; t < 4; t++) {
#pragma unroll
                for (int r = 0; r < 4; r++) {
                    float p = __expf(sc[t][r] - mnew[r]);
                    rsum[r] += p;
                    Pl[w * 16 + quad * 4 + r][t * 16 + c15] = f2bf(p);
                }
            }
#pragma unroll
            for (int r = 0; r < 4; r++) {
                float s = rsum[r];
                s += __shfl_xor(s, 1);
                s += __shfl_xor(s, 2);
                s += __shfl_xor(s, 4);
                s += __shfl_xor(s, 8);
                l_st[r] = l_st[r] * alpha[r] + s;
                m_st[r] = mnew[r];
#pragma unroll
                for (int t = 0; t < 4; t++) Oc[t][r] *= alpha[r];
            }

            bf16x8 ap0 = *reinterpret_cast<const bf16x8*>(&Pl[w * 16 + c15][quad * 8]);
            bf16x8 ap1 = *reinterpret_cast<const bf16x8*>(&Pl[w * 16 + c15][32 + quad * 8]);
#pragma unroll
            for (int t = 0; t < 4; t++) {
                Oc[t] = __builtin_amdgcn_mfma_f32_16x16x32_bf16(ap0, vv0[t], Oc[t], 0, 0, 0);
                Oc[t] = __builtin_amdgcn_mfma_f32_16x16x32_bf16(ap1, vv1[t], Oc[t], 0, 0, 0);
            }
        }

        // Epilogue: stage O into Pl, coalesced uint4 stores.
#pragma unroll
        for (int r = 0; r < 4; r++) {
            float inv = 1.0f / l_st[r];
#pragma unroll
            for (int t = 0; t < 4; t++)
                Pl[w * 16 + quad * 4 + r][t * 16 + c15] = f2bf(Oc[t][r] * inv);
        }
        {
            int row = lane >> 2;
            int ch = lane & 3;
            int gi = i0 + w * 16 + row;
            size_t ob = ((size_t)b * SEQ + gi) * 1024 + h * 64 + ch * 16;
            uint4 v0 = *reinterpret_cast<const uint4*>(&Pl[w * 16 + row][ch * 16]);
            uint4 v1 = *reinterpret_cast<const uint4*>(&Pl[w * 16 + row][ch * 16 + 8]);
            *reinterpret_cast<uint4*>(&ab[ob]) = v0;
            *reinterpret_cast<uint4*>(&ab[ob + 8]) = v1;
        }
    }
}

// MFMA NT-GEMM: out[m,n] = sum_i ab[m,i] * Wo[n,i]; bf16 in, fp32 out.
// Same BK=64 double-buffered gload_lds structure as qkv.
__global__ __launch_bounds__(256) void out_mfma_kernel(
    const unsigned short* __restrict__ A, const unsigned short* __restrict__ Wob,
    float* __restrict__ out)
{
    const int lin = blockIdx.x;
    const int b = lin & 7;
    const int y = lin >> 3;
    const int m0 = y * 128;
    const int n0g = b * 128;

    __shared__ __align__(16) unsigned short As[2][128][64];
    __shared__ __align__(16) unsigned short Bs[2][128][64];

    const int tid = threadIdx.x;
    const int w = tid >> 6;
    const int lane = tid & 63;
    const int quad = lane >> 4;
    const int c15 = lane & 15;
    const int qm = w >> 1, qn = w & 1;
    const int srow8 = lane >> 3;
    const int sch = lane & 7;

    auto stage = [&](int k0, int buf) {
#pragma unroll
        for (int i = 0; i < 4; i++) {
            const int row = i * 32 + w * 8 + srow8;
            const int ch = sch ^ (row & 7);
            gload_lds16(A + (size_t)(m0 + row) * 1024 + k0 + ch * 8,
                        &As[buf][i * 32 + w * 8][0]);
            gload_lds16(Wob + (size_t)(n0g + row) * 1024 + k0 + ch * 8,
                        &Bs[buf][i * 32 + w * 8][0]);
        }
    };

    f32x4 acc[4][4];
#pragma unroll
    for (int mi = 0; mi < 4; mi++)
#pragma unroll
        for (int ni = 0; ni < 4; ni++) acc[mi][ni] = (f32x4){0.f, 0.f, 0.f, 0.f};

    stage(0, 0);
    for (int k0 = 0; k0 < 1024; k0 += 64) {
        const int cb = (k0 >> 6) & 1;
        __syncthreads();
        if (k0 < 960) stage(k0 + 64, cb ^ 1);

        bf16x8 af[2][4], bfr[2][4];
#pragma unroll
        for (int ks = 0; ks < 2; ks++) {
#pragma unroll
            for (int mi = 0; mi < 4; mi++)
                af[ks][mi] = lds_read_swz(As[cb], qm * 64 + mi * 16 + c15, ks * 4 + quad);
#pragma unroll
            for (int ni = 0; ni < 4; ni++)
                bfr[ks][ni] = lds_read_swz(Bs[cb], qn * 64 + ni * 16 + c15, ks * 4 + quad);
        }
#pragma unroll
        for (int ks = 0; ks < 2; ks++)
#pragma unroll
            for (int mi = 0; mi < 4; mi++)
#pragma unroll
                for (int ni = 0; ni < 4; ni++)
                    acc[mi][ni] = __builtin_amdgcn_mfma_f32_16x16x32_bf16(af[ks][mi], bfr[ks][ni], acc[mi][ni], 0, 0, 0);
    }

#pragma unroll
    for (int mi = 0; mi < 4; mi++) {
#pragma unroll
        for (int r = 0; r < 4; r++) {
            int m = m0 + qm * 64 + mi * 16 + quad * 4 + r;
#pragma unroll
            for (int ni = 0; ni < 4; ni++) {
                int n = n0g + qn * 64 + ni * 16 + c15;
                out[(size_t)m * 1024 + n] = acc[mi][ni][r];
            }
        }
    }
}

extern "C" void kernel_launch(void* const* d_in, const int* in_sizes, int n_in,
                              void* d_out, int out_size, void* d_ws, size_t ws_size,
                              hipStream_t stream)
{
    const float* x  = (const float*)d_in[0];
    const float* Wq = (const float*)d_in[1];
    const float* Wk = (const float*)d_in[2];
    const float* Wv = (const float*)d_in[3];
    const float* Wo = (const float*)d_in[4];
    float* out = (float*)d_out;

    const size_t QKV_ELEMS = (size_t)BATCH * SEQ * D_MODEL;  // 4194304

    unsigned short* qb = (unsigned short*)d_ws;
    unsigned short* kb = qb + QKV_ELEMS;
    unsigned short* vt = kb + QKV_ELEMS;   // [b][h][d][s]
    unsigned short* ab = vt + QKV_ELEMS;
    unsigned short* w3bf = ab;             // dead during qkv
    unsigned short* wobf = qb;             // dead during out
    unsigned short* xbuf = (unsigned short*)d_out;  // 8MB of out, dead until out_mfma

    // x (1048576 f4) + Wq/Wk/Wv (3 x 262144 f4) in one launch
    conv4_kernel<<<dim3(7168), 256, 0, stream>>>(x, Wq, Wk, Wv, xbuf, w3bf);
    qkv_mfma_kernel<<<dim3(768), 256, 0, stream>>>(xbuf, w3bf, qb, kb, vt);
    attn_kernel<<<dim3(16, 32), 256, 0, stream>>>(qb, kb, vt, ab);
    conv_kernel<<<dim3(1024), 256, 0, stream>>>(Wo, wobf, 262144);
    out_mfma_kernel<<<dim3(256), 256, 0, stream>>>(ab, wobf, out);
}

// Round 4
// 218.266 us; speedup vs baseline: 1.3284x; 1.0890x over previous
//
#include <hip/hip_runtime.h>

#define D_MODEL 1024
#define NUM_HEADS 16
#define SEQ 2048
#define BATCH 2

typedef __attribute__((ext_vector_type(8))) short bf16x8;
typedef __attribute__((ext_vector_type(4))) float f32x4;

__device__ __forceinline__ float bf2f(unsigned short u) {
    return __uint_as_float(((unsigned int)u) << 16);
}
__device__ __forceinline__ unsigned short f2bf(float f) {
    unsigned int u = __float_as_uint(f);
    return (unsigned short)((u + 0x7FFFu + ((u >> 16) & 1u)) >> 16);   // RTNE
}
__device__ __forceinline__ ushort4 pack4(float4 v) {
    return make_ushort4(f2bf(v.x), f2bf(v.y), f2bf(v.z), f2bf(v.w));
}

// async global->LDS, 16B per lane. LDS dest = wave-uniform base + lane*16.
__device__ __forceinline__ void gload_lds16(const unsigned short* g, unsigned short* l) {
    __builtin_amdgcn_global_load_lds(
        (const __attribute__((address_space(1))) unsigned int*)g,
        (__attribute__((address_space(3))) unsigned int*)l,
        16, 0, 0);
}

// Swizzled 16B read from a [N][64] bf16 LDS tile (128B rows, 8 chunks).
// LDS[row][chunk] holds G[row][chunk ^ (row&7)] (established by pre-swizzling
// the global source in the staging loads), so reading chunk^(row&7) recovers
// the logical element and is bank-conflict-free (2-way) across 16 rows.
__device__ __forceinline__ bf16x8 lds_read_swz(const unsigned short (*tile)[64], int row, int chunk) {
    const char* p = reinterpret_cast<const char*>(tile);
    return *reinterpret_cast<const bf16x8*>(p + row * 128 + (((chunk ^ (row & 7))) << 4));
}

// fp32 -> bf16 bulk convert (one float4 -> ushort4 per thread).
__global__ __launch_bounds__(256) void conv_kernel(
    const float* __restrict__ src, unsigned short* __restrict__ dst, int n4)
{
    int i = blockIdx.x * 256 + threadIdx.x;
    if (i < n4) {
        float4 v = reinterpret_cast<const float4*>(src)[i];
        reinterpret_cast<ushort4*>(dst)[i] = pack4(v);
    }
}

// Fused conversion of x (1048576 float4) + Wq/Wk/Wv (262144 float4 each).
__global__ __launch_bounds__(256) void conv4_kernel(
    const float* __restrict__ x, const float* __restrict__ Wq,
    const float* __restrict__ Wk, const float* __restrict__ Wv,
    unsigned short* __restrict__ xb, unsigned short* __restrict__ w3bf)
{
    int i = blockIdx.x * 256 + threadIdx.x;
    const float* src;
    unsigned short* dst;
    int off;
    if (i < 1048576) {
        src = x; dst = xb; off = i;
    } else {
        int j = i - 1048576;
        int which = j >> 18;            // 262144 = 2^18
        off = j & 0x3FFFF;
        src = (which == 0) ? Wq : (which == 1) ? Wk : Wv;
        dst = w3bf + ((size_t)which << 20);   // 1048576 ushorts per W
    }
    float4 v = reinterpret_cast<const float4*>(src)[off];
    reinterpret_cast<ushort4*>(dst)[off] = pack4(v);
}

// MFMA NT-GEMM: C[m,n] = sum_i xb[m,i] * W[n,i], all bf16.
// 128x128 tile, BK=64, double-buffered global_load_lds staging with the
// inverse-swizzled-source + swizzled-read XOR layout (conflict-free ds_read).
// Q,K: RoPE fused, [b][h][s][d]. V: TRANSPOSED write [b][h][d][s].
__global__ __launch_bounds__(256) void qkv_mfma_kernel(
    const unsigned short* __restrict__ xb,   // [4096][1024] bf16
    const unsigned short* __restrict__ w3,   // [3][1024][1024] bf16
    unsigned short* __restrict__ qb, unsigned short* __restrict__ kb,
    unsigned short* __restrict__ vt)
{
    const int lin = blockIdx.x;
    const int b = lin & 7;
    const int t = lin >> 3;
    const int which = t % 3;
    const int y = t / 3;
    const unsigned short* __restrict__ W = w3 + (size_t)which * 1048576;
    const int m0 = y * 128;
    const int n0g = b * 128;

    __shared__ __align__(16) unsigned short As[2][128][64];  // 32 KB
    __shared__ __align__(16) unsigned short Bs[2][128][64];  // 32 KB

    const int tid = threadIdx.x;
    const int w = tid >> 6;
    const int lane = tid & 63;
    const int quad = lane >> 4;
    const int c15 = lane & 15;
    const int qm = w >> 1, qn = w & 1;
    const int srow8 = lane >> 3;   // row within an 8-row staging instruction
    const int sch = lane & 7;      // 16B chunk within a 128B row

    auto stage = [&](int k0, int buf) {
#pragma unroll
        for (int i = 0; i < 4; i++) {
            const int row = i * 32 + w * 8 + srow8;
            const int ch = sch ^ (row & 7);
            gload_lds16(xb + (size_t)(m0 + row) * 1024 + k0 + ch * 8,
                        &As[buf][i * 32 + w * 8][0]);
            gload_lds16(W + (size_t)(n0g + row) * 1024 + k0 + ch * 8,
                        &Bs[buf][i * 32 + w * 8][0]);
        }
    };

    f32x4 acc[4][4];
#pragma unroll
    for (int mi = 0; mi < 4; mi++)
#pragma unroll
        for (int ni = 0; ni < 4; ni++) acc[mi][ni] = (f32x4){0.f, 0.f, 0.f, 0.f};

    stage(0, 0);
    for (int k0 = 0; k0 < 1024; k0 += 64) {
        const int cb = (k0 >> 6) & 1;
        __syncthreads();                       // staging of cb complete
        if (k0 < 960) stage(k0 + 64, cb ^ 1);  // prefetch; drains at next barrier

        bf16x8 af[2][4], bfr[2][4];
#pragma unroll
        for (int ks = 0; ks < 2; ks++) {
#pragma unroll
            for (int mi = 0; mi < 4; mi++)
                af[ks][mi] = lds_read_swz(As[cb], qm * 64 + mi * 16 + c15, ks * 4 + quad);
#pragma unroll
            for (int ni = 0; ni < 4; ni++)
                bfr[ks][ni] = lds_read_swz(Bs[cb], qn * 64 + ni * 16 + c15, ks * 4 + quad);
        }
#pragma unroll
        for (int ks = 0; ks < 2; ks++)
#pragma unroll
            for (int mi = 0; mi < 4; mi++)
#pragma unroll
                for (int ni = 0; ni < 4; ni++)
                    acc[mi][ni] = __builtin_amdgcn_mfma_f32_16x16x32_bf16(af[ks][mi], bfr[ks][ni], acc[mi][ni], 0, 0, 0);
    }

    // Epilogue: RoPE (Q,K) in registers -> wave-private LDS stage -> coalesced
    // stores. Wave's n-range = one head: h = b*2 + qn.
    __syncthreads();
    unsigned short* stg = &As[0][0][0] + w * (16 * 72);   // 16 rows x 72 stride, per wave
    const int hq = b * 2 + qn;
    unsigned short* outp = (which == 0) ? qb : kb;

    float invf[4];
#pragma unroll
    for (int ni = 0; ni < 4; ni++)
        invf[ni] = powf(10000.0f, -((float)(((ni * 16 + c15) & 63) >> 1)) / 32.0f);
    const int odd = c15 & 1;

#pragma unroll
    for (int mi = 0; mi < 4; mi++) {
#pragma unroll
        for (int r = 0; r < 4; r++) {
            int m = m0 + qm * 64 + mi * 16 + quad * 4 + r;
            int s = m & (SEQ - 1);
#pragma unroll
            for (int ni = 0; ni < 4; ni++) {
                float val = acc[mi][ni][r];
                float res;
                if (which < 2) {
                    float part = __shfl_xor(val, 1);
                    float sn, cs;
                    sincosf((float)s * invf[ni], &sn, &cs);
                    res = odd ? (part * sn + val * cs) : (val * cs - part * sn);
                } else {
                    res = val;
                }
                stg[(quad * 4 + r) * 72 + ni * 16 + c15] = f2bf(res);
            }
        }
        if (which < 2) {
            int row = lane >> 2;
            int ch = lane & 3;
            int m = m0 + qm * 64 + mi * 16 + row;
            int s = m & (SEQ - 1);
            int bb = m >> 11;
            size_t ob = (((size_t)bb * NUM_HEADS + hq) * SEQ + s) * 64 + ch * 16;
            uint4 v0 = *reinterpret_cast<const uint4*>(&stg[row * 72 + ch * 16]);
            uint4 v1 = *reinterpret_cast<const uint4*>(&stg[row * 72 + ch * 16 + 8]);
            *reinterpret_cast<uint4*>(&outp[ob]) = v0;
            *reinterpret_cast<uint4*>(&outp[ob + 8]) = v1;
        } else {
            int mbase = m0 + qm * 64 + mi * 16;
            int bb = mbase >> 11;
            int s_base = mbase & (SEQ - 1);
            unsigned short tmp[16];
#pragma unroll
            for (int sl = 0; sl < 16; sl++) tmp[sl] = stg[sl * 72 + lane];
            size_t ob = (((size_t)bb * NUM_HEADS + hq) * 64 + lane) * SEQ + s_base;
            *reinterpret_cast<uint4*>(&vt[ob])     = *reinterpret_cast<uint4*>(&tmp[0]);
            *reinterpret_cast<uint4*>(&vt[ob + 8]) = *reinterpret_cast<uint4*>(&tmp[8]);
        }
    }
}

// MFMA flash attention with SWAPPED-operand softmax.
// S^T = mfma(K, Q): lane's c15 = its q-row; the 16 registers hold 16 j-values
// (j = t*16 + quad*4 + r). Row-max needs only an in-register tree + 2
// cross-quad shuffles; row-sum butterfly defers to the epilogue (0 per-iter
// shuffles). PV is swapped too (O^T = mfma(V^T, P)), so m/l/alpha are
// lane-local scalars. Defer-max (THR = 64 raw = 8 scaled) skips the O-rescale
// pass on almost every iteration.
__global__ __launch_bounds__(256) void attn_kernel(
    const unsigned short* __restrict__ qb, const unsigned short* __restrict__ kb,
    const unsigned short* __restrict__ vt, unsigned short* __restrict__ ab)
{
    const int xpair = blockIdx.x;   // 0..15
    const int bh = blockIdx.y;
    const int b = bh >> 4, h = bh & 15;
    const size_t base = (size_t)bh * SEQ * 64;     // qb/kb [b][h][s][d]
    const size_t vbase = (size_t)bh * 64 * SEQ;    // vt [b][h][d][s]
    const int tid = threadIdx.x;
    const int w = tid >> 6;
    const int lane = tid & 63;
    const int quad = lane >> 4;
    const int c15 = lane & 15;
    const int srow8 = lane >> 3;
    const int sch = lane & 7;
    const float C = 0.125f;   // softmax scale 1/sqrt(64)

    __shared__ __align__(16) unsigned short Ks[2][64][64];   // [buf][j][d]
    __shared__ __align__(16) unsigned short Vs[2][64][64];   // [buf][d][j]
    __shared__ __align__(16) unsigned short Pl[64][72];      // wave-private rows

    auto stage = [&](int jts, int buf) {
        const int j0s = jts * 64;
#pragma unroll
        for (int i = 0; i < 2; i++) {
            const int row = w * 16 + i * 8 + srow8;
            const int ch = sch ^ (row & 7);
            gload_lds16(kb + base + (size_t)(j0s + row) * 64 + ch * 8,
                        &Ks[buf][w * 16 + i * 8][0]);
            gload_lds16(vt + vbase + (size_t)row * SEQ + j0s + ch * 8,
                        &Vs[buf][w * 16 + i * 8][0]);
        }
    };

    for (int pass = 0; pass < 2; pass++) {
        const int it = pass ? xpair : (31 - xpair);   // heavy tile first
        const int i0 = it * 64;

        const int qrow = i0 + w * 16 + c15;
        bf16x8 qf0 = *reinterpret_cast<const bf16x8*>(&qb[base + (size_t)qrow * 64 + quad * 8]);
        bf16x8 qf1 = *reinterpret_cast<const bf16x8*>(&qb[base + (size_t)qrow * 64 + 32 + quad * 8]);

        float m_st = -1e30f, l_st = 0.f;    // lane-local: q-row = c15
        f32x4 Oc[4];                        // Oc[t][r]: d = t*16+quad*4+r, q = c15
#pragma unroll
        for (int t = 0; t < 4; t++) Oc[t] = (f32x4){0.f, 0.f, 0.f, 0.f};

        __syncthreads();          // prev pass done reading buffers
        stage(0, 0);              // prologue: tile 0 -> buf 0

        for (int jt = 0; jt <= it; jt++) {
            const int j0 = jt * 64;
            const int cb = jt & 1;

            __syncthreads();      // staging for cb complete; nb free to overwrite
            if (jt < it) stage(jt + 1, cb ^ 1);

            bf16x8 kc0[4], kc1[4];
#pragma unroll
            for (int t = 0; t < 4; t++) {
                kc0[t] = lds_read_swz(Ks[cb], t * 16 + c15, quad);
                kc1[t] = lds_read_swz(Ks[cb], t * 16 + c15, 4 + quad);
            }

            // S^T[j][q]: sc[t][r] = S[j = j0+t*16+quad*4+r][q-row = c15] (raw)
            f32x4 sc[4];
#pragma unroll
            for (int t = 0; t < 4; t++) sc[t] = (f32x4){0.f, 0.f, 0.f, 0.f};
#pragma unroll
            for (int t = 0; t < 4; t++) {
                sc[t] = __builtin_amdgcn_mfma_f32_16x16x32_bf16(kc0[t], qf0, sc[t], 0, 0, 0);
                sc[t] = __builtin_amdgcn_mfma_f32_16x16x32_bf16(kc1[t], qf1, sc[t], 0, 0, 0);
            }

            bf16x8 vv0[4], vv1[4];
#pragma unroll
            for (int t = 0; t < 4; t++) {
                vv0[t] = lds_read_swz(Vs[cb], t * 16 + c15, quad);
                vv1[t] = lds_read_swz(Vs[cb], t * 16 + c15, 4 + quad);
            }

            if (jt == it) {
                const int gi = i0 + w * 16 + c15;
#pragma unroll
                for (int t = 0; t < 4; t++) {
#pragma unroll
                    for (int r = 0; r < 4; r++) {
                        int gj = j0 + t * 16 + quad * 4 + r;
                        if (gj > gi) sc[t][r] = -1e30f;
                    }
                }
            }

            // row-max: in-register tree over 16 j-values + 2 cross-quad shuffles
            float x0 = fmaxf(fmaxf(sc[0][0], sc[0][1]), fmaxf(sc[0][2], sc[0][3]));
            float x1 = fmaxf(fmaxf(sc[1][0], sc[1][1]), fmaxf(sc[1][2], sc[1][3]));
            float x2 = fmaxf(fmaxf(sc[2][0], sc[2][1]), fmaxf(sc[2][2], sc[2][3]));
            float x3 = fmaxf(fmaxf(sc[3][0], sc[3][1]), fmaxf(sc[3][2], sc[3][3]));
            float tm = fmaxf(fmaxf(x0, x1), fmaxf(x2, x3));
            tm = fmaxf(tm, __shfl_xor(tm, 16));
            tm = fmaxf(tm, __shfl_xor(tm, 32));

            // defer-max: skip rescale unless max grew by > 64 raw (8 scaled)
            if (!__all(tm <= m_st + 64.0f)) {
                float mnew = fmaxf(m_st, tm);
                float alpha = __expf((m_st - mnew) * C);
                l_st *= alpha;
#pragma unroll
                for (int t = 0; t < 4; t++)
#pragma unroll
                    for (int r = 0; r < 4; r++) Oc[t][r] *= alpha;
                m_st = mnew;
            }

            const float mC = m_st * C;
            float p[4][4];
#pragma unroll
            for (int t = 0; t < 4; t++)
#pragma unroll
                for (int r = 0; r < 4; r++)
                    p[t][r] = __expf(__builtin_fmaf(sc[t][r], C, -mC));

            // partial row-sum (this quad's 16 j's); butterfly deferred to epilogue
            float s0 = (p[0][0] + p[0][1]) + (p[0][2] + p[0][3]);
            float s1 = (p[1][0] + p[1][1]) + (p[1][2] + p[1][3]);
            float s2 = (p[2][0] + p[2][1]) + (p[2][2] + p[2][3]);
            float s3 = (p[3][0] + p[3][1]) + (p[3][2] + p[3][3]);
            l_st += (s0 + s1) + (s2 + s3);

            // P[q][j] -> wave-private LDS, packed b32 pairs
#pragma unroll
            for (int t = 0; t < 4; t++) {
#pragma unroll
                for (int hh = 0; hh < 2; hh++) {
                    unsigned int pk = (unsigned int)f2bf(p[t][2 * hh])
                                    | ((unsigned int)f2bf(p[t][2 * hh + 1]) << 16);
                    *reinterpret_cast<unsigned int*>(
                        &Pl[w * 16 + c15][t * 16 + quad * 4 + 2 * hh]) = pk;
                }
            }

            bf16x8 ap0 = *reinterpret_cast<const bf16x8*>(&Pl[w * 16 + c15][quad * 8]);
            bf16x8 ap1 = *reinterpret_cast<const bf16x8*>(&Pl[w * 16 + c15][32 + quad * 8]);
#pragma unroll
            for (int t = 0; t < 4; t++) {
                Oc[t] = __builtin_amdgcn_mfma_f32_16x16x32_bf16(vv0[t], ap0, Oc[t], 0, 0, 0);
                Oc[t] = __builtin_amdgcn_mfma_f32_16x16x32_bf16(vv1[t], ap1, Oc[t], 0, 0, 0);
            }
        }

        // epilogue: finish l across quads, normalize, stage, coalesced store
        l_st += __shfl_xor(l_st, 16);
        l_st += __shfl_xor(l_st, 32);
        float inv = 1.0f / l_st;
#pragma unroll
        for (int t = 0; t < 4; t++) {
#pragma unroll
            for (int hh = 0; hh < 2; hh++) {
                unsigned int pk = (unsigned int)f2bf(Oc[t][2 * hh] * inv)
                                | ((unsigned int)f2bf(Oc[t][2 * hh + 1] * inv) << 16);
                *reinterpret_cast<unsigned int*>(
                    &Pl[w * 16 + c15][t * 16 + quad * 4 + 2 * hh]) = pk;
            }
        }
        {
            int row = lane >> 2;
            int ch = lane & 3;
            int gi = i0 + w * 16 + row;
            size_t ob = ((size_t)b * SEQ + gi) * 1024 + h * 64 + ch * 16;
            uint4 v0 = *reinterpret_cast<const uint4*>(&Pl[w * 16 + row][ch * 16]);
            uint4 v1 = *reinterpret_cast<const uint4*>(&Pl[w * 16 + row][ch * 16 + 8]);
            *reinterpret_cast<uint4*>(&ab[ob]) = v0;
            *reinterpret_cast<uint4*>(&ab[ob + 8]) = v1;
        }
    }
}

// MFMA NT-GEMM: out[m,n] = sum_i ab[m,i] * Wo[n,i]; bf16 in, fp32 out.
__global__ __launch_bounds__(256) void out_mfma_kernel(
    const unsigned short* __restrict__ A, const unsigned short* __restrict__ Wob,
    float* __restrict__ out)
{
    const int lin = blockIdx.x;
    const int b = lin & 7;
    const int y = lin >> 3;
    const int m0 = y * 128;
    const int n0g = b * 128;

    __shared__ __align__(16) unsigned short As[2][128][64];
    __shared__ __align__(16) unsigned short Bs[2][128][64];

    const int tid = threadIdx.x;
    const int w = tid >> 6;
    const int lane = tid & 63;
    const int quad = lane >> 4;
    const int c15 = lane & 15;
    const int qm = w >> 1, qn = w & 1;
    const int srow8 = lane >> 3;
    const int sch = lane & 7;

    auto stage = [&](int k0, int buf) {
#pragma unroll
        for (int i = 0; i < 4; i++) {
            const int row = i * 32 + w * 8 + srow8;
            const int ch = sch ^ (row & 7);
            gload_lds16(A + (size_t)(m0 + row) * 1024 + k0 + ch * 8,
                        &As[buf][i * 32 + w * 8][0]);
            gload_lds16(Wob + (size_t)(n0g + row) * 1024 + k0 + ch * 8,
                        &Bs[buf][i * 32 + w * 8][0]);
        }
    };

    f32x4 acc[4][4];
#pragma unroll
    for (int mi = 0; mi < 4; mi++)
#pragma unroll
        for (int ni = 0; ni < 4; ni++) acc[mi][ni] = (f32x4){0.f, 0.f, 0.f, 0.f};

    stage(0, 0);
    for (int k0 = 0; k0 < 1024; k0 += 64) {
        const int cb = (k0 >> 6) & 1;
        __syncthreads();
        if (k0 < 960) stage(k0 + 64, cb ^ 1);

        bf16x8 af[2][4], bfr[2][4];
#pragma unroll
        for (int ks = 0; ks < 2; ks++) {
#pragma unroll
            for (int mi = 0; mi < 4; mi++)
                af[ks][mi] = lds_read_swz(As[cb], qm * 64 + mi * 16 + c15, ks * 4 + quad);
#pragma unroll
            for (int ni = 0; ni < 4; ni++)
                bfr[ks][ni] = lds_read_swz(Bs[cb], qn * 64 + ni * 16 + c15, ks * 4 + quad);
        }
#pragma unroll
        for (int ks = 0; ks < 2; ks++)
#pragma unroll
            for (int mi = 0; mi < 4; mi++)
#pragma unroll
                for (int ni = 0; ni < 4; ni++)
                    acc[mi][ni] = __builtin_amdgcn_mfma_f32_16x16x32_bf16(af[ks][mi], bfr[ks][ni], acc[mi][ni], 0, 0, 0);
    }

#pragma unroll
    for (int mi = 0; mi < 4; mi++) {
#pragma unroll
        for (int r = 0; r < 4; r++) {
            int m = m0 + qm * 64 + mi * 16 + quad * 4 + r;
#pragma unroll
            for (int ni = 0; ni < 4; ni++) {
                int n = n0g + qn * 64 + ni * 16 + c15;
                out[(size_t)m * 1024 + n] = acc[mi][ni][r];
            }
        }
    }
}

extern "C" void kernel_launch(void* const* d_in, const int* in_sizes, int n_in,
                              void* d_out, int out_size, void* d_ws, size_t ws_size,
                              hipStream_t stream)
{
    const float* x  = (const float*)d_in[0];
    const float* Wq = (const float*)d_in[1];
    const float* Wk = (const float*)d_in[2];
    const float* Wv = (const float*)d_in[3];
    const float* Wo = (const float*)d_in[4];
    float* out = (float*)d_out;

    const size_t QKV_ELEMS = (size_t)BATCH * SEQ * D_MODEL;  // 4194304

    unsigned short* qb = (unsigned short*)d_ws;
    unsigned short* kb = qb + QKV_ELEMS;
    unsigned short* vt = kb + QKV_ELEMS;   // [b][h][d][s]
    unsigned short* ab = vt + QKV_ELEMS;
    unsigned short* w3bf = ab;             // dead during qkv
    unsigned short* wobf = qb;             // dead during out
    unsigned short* xbuf = (unsigned short*)d_out;  // 8MB of out, dead until out_mfma

    conv4_kernel<<<dim3(7168), 256, 0, stream>>>(x, Wq, Wk, Wv, xbuf, w3bf);
    qkv_mfma_kernel<<<dim3(768), 256, 0, stream>>>(xbuf, w3bf, qb, kb, vt);
    attn_kernel<<<dim3(16, 32), 256, 0, stream>>>(qb, kb, vt, ab);
    conv_kernel<<<dim3(1024), 256, 0, stream>>>(Wo, wobf, 262144);
    out_mfma_kernel<<<dim3(256), 256, 0, stream>>>(ab, wobf, out);
}

// Round 5
// 215.742 us; speedup vs baseline: 1.3440x; 1.0117x over previous
//
#include <hip/hip_runtime.h>

#define D_MODEL 1024
#define NUM_HEADS 16
#define SEQ 2048
#define BATCH 2

typedef __attribute__((ext_vector_type(8))) short bf16x8;
typedef __attribute__((ext_vector_type(4))) float f32x4;

__device__ __forceinline__ float bf2f(unsigned short u) {
    return __uint_as_float(((unsigned int)u) << 16);
}
__device__ __forceinline__ unsigned short f2bf(float f) {
    unsigned int u = __float_as_uint(f);
    return (unsigned short)((u + 0x7FFFu + ((u >> 16) & 1u)) >> 16);   // RTNE
}
__device__ __forceinline__ ushort4 pack4(float4 v) {
    return make_ushort4(f2bf(v.x), f2bf(v.y), f2bf(v.z), f2bf(v.w));
}

// async global->LDS, 16B per lane. LDS dest = wave-uniform base + lane*16.
__device__ __forceinline__ void gload_lds16(const unsigned short* g, unsigned short* l) {
    __builtin_amdgcn_global_load_lds(
        (const __attribute__((address_space(1))) unsigned int*)g,
        (__attribute__((address_space(3))) unsigned int*)l,
        16, 0, 0);
}

// Swizzled 16B read from a [N][64] bf16 LDS tile (128B rows, 8 chunks).
// LDS[row][chunk] holds G[row][chunk ^ (row&7)] (established by pre-swizzling
// the global source in the staging loads), so reading chunk^(row&7) recovers
// the logical element and is bank-conflict-free (2-way) across 16 rows.
__device__ __forceinline__ bf16x8 lds_read_swz(const unsigned short (*tile)[64], int row, int chunk) {
    const char* p = reinterpret_cast<const char*>(tile);
    return *reinterpret_cast<const bf16x8*>(p + row * 128 + (((chunk ^ (row & 7))) << 4));
}

// fp32 -> bf16 bulk convert (one float4 -> ushort4 per thread).
__global__ __launch_bounds__(256) void conv_kernel(
    const float* __restrict__ src, unsigned short* __restrict__ dst, int n4)
{
    int i = blockIdx.x * 256 + threadIdx.x;
    if (i < n4) {
        float4 v = reinterpret_cast<const float4*>(src)[i];
        reinterpret_cast<ushort4*>(dst)[i] = pack4(v);
    }
}

// Fused conversion of x (1048576 float4) + Wq/Wk/Wv (262144 float4 each)
// + RoPE cos/sin table build (2048 x 32 float2).
__global__ __launch_bounds__(256) void conv4_kernel(
    const float* __restrict__ x, const float* __restrict__ Wq,
    const float* __restrict__ Wk, const float* __restrict__ Wv,
    unsigned short* __restrict__ xb, unsigned short* __restrict__ w3bf,
    float2* __restrict__ tab)
{
    int i = blockIdx.x * 256 + threadIdx.x;
    if (i < 1835008) {
        const float* src;
        unsigned short* dst;
        int off;
        if (i < 1048576) {
            src = x; dst = xb; off = i;
        } else {
            int j = i - 1048576;
            int which = j >> 18;            // 262144 = 2^18
            off = j & 0x3FFFF;
            src = (which == 0) ? Wq : (which == 1) ? Wk : Wv;
            dst = w3bf + ((size_t)which << 20);   // 1048576 ushorts per W
        }
        float4 v = reinterpret_cast<const float4*>(src)[off];
        reinterpret_cast<ushort4*>(dst)[off] = pack4(v);
    } else {
        int idx = i - 1835008;              // 65536 entries
        int s = idx >> 5, d2 = idx & 31;
        float inv = powf(10000.0f, -(float)d2 / 32.0f);
        float sn, cs;
        sincosf((float)s * inv, &sn, &cs);
        tab[idx] = make_float2(cs, sn);
    }
}

// MFMA NT-GEMM: C[m,n] = sum_i xb[m,i] * W[n,i], all bf16.
// 128x128 tile, BK=64, double-buffered global_load_lds staging with the
// inverse-swizzled-source + swizzled-read XOR layout (conflict-free ds_read).
// Q,K: RoPE fused (table-based, no trig), [b][h][s][d]. V: TRANSPOSED
// write [b][h][d][s].
__global__ __launch_bounds__(256) void qkv_mfma_kernel(
    const unsigned short* __restrict__ xb,   // [4096][1024] bf16
    const unsigned short* __restrict__ w3,   // [3][1024][1024] bf16
    const float2* __restrict__ tab,          // [2048][32] cos,sin
    unsigned short* __restrict__ qb, unsigned short* __restrict__ kb,
    unsigned short* __restrict__ vt)
{
    const int lin = blockIdx.x;
    const int b = lin & 7;
    const int t = lin >> 3;
    const int which = t % 3;
    const int y = t / 3;
    const unsigned short* __restrict__ W = w3 + (size_t)which * 1048576;
    const int m0 = y * 128;
    const int n0g = b * 128;

    __shared__ __align__(16) unsigned short As[2][128][64];  // 32 KB
    __shared__ __align__(16) unsigned short Bs[2][128][64];  // 32 KB

    const int tid = threadIdx.x;
    const int w = tid >> 6;
    const int lane = tid & 63;
    const int quad = lane >> 4;
    const int c15 = lane & 15;
    const int qm = w >> 1, qn = w & 1;
    const int srow8 = lane >> 3;   // row within an 8-row staging instruction
    const int sch = lane & 7;      // 16B chunk within a 128B row

    auto stage = [&](int k0, int buf) {
#pragma unroll
        for (int i = 0; i < 4; i++) {
            const int row = i * 32 + w * 8 + srow8;
            const int ch = sch ^ (row & 7);
            gload_lds16(xb + (size_t)(m0 + row) * 1024 + k0 + ch * 8,
                        &As[buf][i * 32 + w * 8][0]);
            gload_lds16(W + (size_t)(n0g + row) * 1024 + k0 + ch * 8,
                        &Bs[buf][i * 32 + w * 8][0]);
        }
    };

    f32x4 acc[4][4];
#pragma unroll
    for (int mi = 0; mi < 4; mi++)
#pragma unroll
        for (int ni = 0; ni < 4; ni++) acc[mi][ni] = (f32x4){0.f, 0.f, 0.f, 0.f};

    stage(0, 0);
    for (int k0 = 0; k0 < 1024; k0 += 64) {
        const int cb = (k0 >> 6) & 1;
        __syncthreads();                       // staging of cb complete
        if (k0 < 960) stage(k0 + 64, cb ^ 1);  // prefetch; drains at next barrier

        bf16x8 af[2][4], bfr[2][4];
#pragma unroll
        for (int ks = 0; ks < 2; ks++) {
#pragma unroll
            for (int mi = 0; mi < 4; mi++)
                af[ks][mi] = lds_read_swz(As[cb], qm * 64 + mi * 16 + c15, ks * 4 + quad);
#pragma unroll
            for (int ni = 0; ni < 4; ni++)
                bfr[ks][ni] = lds_read_swz(Bs[cb], qn * 64 + ni * 16 + c15, ks * 4 + quad);
        }
#pragma unroll
        for (int ks = 0; ks < 2; ks++)
#pragma unroll
            for (int mi = 0; mi < 4; mi++)
#pragma unroll
                for (int ni = 0; ni < 4; ni++)
                    acc[mi][ni] = __builtin_amdgcn_mfma_f32_16x16x32_bf16(af[ks][mi], bfr[ks][ni], acc[mi][ni], 0, 0, 0);
    }

    // Epilogue: RoPE (Q,K) via cos/sin table -> wave-private LDS stage ->
    // coalesced stores. Wave's n-range = one head: h = b*2 + qn.
    __syncthreads();
    unsigned short* stg = &As[0][0][0] + w * (16 * 72);   // 16 rows x 72 stride, per wave
    const int hq = b * 2 + qn;
    unsigned short* outp = (which == 0) ? qb : kb;
    const int odd = c15 & 1;

#pragma unroll
    for (int mi = 0; mi < 4; mi++) {
#pragma unroll
        for (int r = 0; r < 4; r++) {
            int m = m0 + qm * 64 + mi * 16 + quad * 4 + r;
            int s = m & (SEQ - 1);
            const float2* trow = tab + (s << 5);
#pragma unroll
            for (int ni = 0; ni < 4; ni++) {
                float val = acc[mi][ni][r];
                float res;
                if (which < 2) {
                    float part = __shfl_xor(val, 1);
                    float2 cs = trow[(ni * 16 + c15) >> 1];
                    res = odd ? (part * cs.y + val * cs.x) : (val * cs.x - part * cs.y);
                } else {
                    res = val;
                }
                stg[(quad * 4 + r) * 72 + ni * 16 + c15] = f2bf(res);
            }
        }
        if (which < 2) {
            int row = lane >> 2;
            int ch = lane & 3;
            int m = m0 + qm * 64 + mi * 16 + row;
            int s = m & (SEQ - 1);
            int bb = m >> 11;
            size_t ob = (((size_t)bb * NUM_HEADS + hq) * SEQ + s) * 64 + ch * 16;
            uint4 v0 = *reinterpret_cast<const uint4*>(&stg[row * 72 + ch * 16]);
            uint4 v1 = *reinterpret_cast<const uint4*>(&stg[row * 72 + ch * 16 + 8]);
            *reinterpret_cast<uint4*>(&outp[ob]) = v0;
            *reinterpret_cast<uint4*>(&outp[ob + 8]) = v1;
        } else {
            int mbase = m0 + qm * 64 + mi * 16;
            int bb = mbase >> 11;
            int s_base = mbase & (SEQ - 1);
            unsigned short tmp[16];
#pragma unroll
            for (int sl = 0; sl < 16; sl++) tmp[sl] = stg[sl * 72 + lane];
            size_t ob = (((size_t)bb * NUM_HEADS + hq) * 64 + lane) * SEQ + s_base;
            *reinterpret_cast<uint4*>(&vt[ob])     = *reinterpret_cast<uint4*>(&tmp[0]);
            *reinterpret_cast<uint4*>(&vt[ob + 8]) = *reinterpret_cast<uint4*>(&tmp[8]);
        }
    }
}

// MFMA flash attention with SWAPPED-operand softmax.
// S^T = mfma(K, Q): lane's c15 = its q-row; the 16 registers hold 16 j-values
// (j = t*16 + quad*4 + r). Row-max needs only an in-register tree + 2
// cross-quad shuffles; row-sum butterfly defers to the epilogue (0 per-iter
// shuffles). PV is swapped too (O^T = mfma(V^T, P)), so m/l/alpha are
// lane-local scalars. Defer-max (THR = 64 raw = 8 scaled) skips the O-rescale
// pass on almost every iteration.
__global__ __launch_bounds__(256) void attn_kernel(
    const unsigned short* __restrict__ qb, const unsigned short* __restrict__ kb,
    const unsigned short* __restrict__ vt, unsigned short* __restrict__ ab)
{
    const int xpair = blockIdx.x;   // 0..15
    const int bh = blockIdx.y;
    const int b = bh >> 4, h = bh & 15;
    const size_t base = (size_t)bh * SEQ * 64;     // qb/kb [b][h][s][d]
    const size_t vbase = (size_t)bh * 64 * SEQ;    // vt [b][h][d][s]
    const int tid = threadIdx.x;
    const int w = tid >> 6;
    const int lane = tid & 63;
    const int quad = lane >> 4;
    const int c15 = lane & 15;
    const int srow8 = lane >> 3;
    const int sch = lane & 7;
    const float C = 0.125f;   // softmax scale 1/sqrt(64)

    __shared__ __align__(16) unsigned short Ks[2][64][64];   // [buf][j][d]
    __shared__ __align__(16) unsigned short Vs[2][64][64];   // [buf][d][j]
    __shared__ __align__(16) unsigned short Pl[64][72];      // wave-private rows

    auto stage = [&](int jts, int buf) {
        const int j0s = jts * 64;
#pragma unroll
        for (int i = 0; i < 2; i++) {
            const int row = w * 16 + i * 8 + srow8;
            const int ch = sch ^ (row & 7);
            gload_lds16(kb + base + (size_t)(j0s + row) * 64 + ch * 8,
                        &Ks[buf][w * 16 + i * 8][0]);
            gload_lds16(vt + vbase + (size_t)row * SEQ + j0s + ch * 8,
                        &Vs[buf][w * 16 + i * 8][0]);
        }
    };

    for (int pass = 0; pass < 2; pass++) {
        const int it = pass ? xpair : (31 - xpair);   // heavy tile first
        const int i0 = it * 64;

        const int qrow = i0 + w * 16 + c15;
        bf16x8 qf0 = *reinterpret_cast<const bf16x8*>(&qb[base + (size_t)qrow * 64 + quad * 8]);
        bf16x8 qf1 = *reinterpret_cast<const bf16x8*>(&qb[base + (size_t)qrow * 64 + 32 + quad * 8]);

        float m_st = -1e30f, l_st = 0.f;    // lane-local: q-row = c15
        f32x4 Oc[4];                        // Oc[t][r]: d = t*16+quad*4+r, q = c15
#pragma unroll
        for (int t = 0; t < 4; t++) Oc[t] = (f32x4){0.f, 0.f, 0.f, 0.f};

        __syncthreads();          // prev pass done reading buffers
        stage(0, 0);              // prologue: tile 0 -> buf 0

        for (int jt = 0; jt <= it; jt++) {
            const int j0 = jt * 64;
            const int cb = jt & 1;

            __syncthreads();      // staging for cb complete; nb free to overwrite
            if (jt < it) stage(jt + 1, cb ^ 1);

            bf16x8 kc0[4], kc1[4];
#pragma unroll
            for (int t = 0; t < 4; t++) {
                kc0[t] = lds_read_swz(Ks[cb], t * 16 + c15, quad);
                kc1[t] = lds_read_swz(Ks[cb], t * 16 + c15, 4 + quad);
            }

            // S^T[j][q]: sc[t][r] = S[j = j0+t*16+quad*4+r][q-row = c15] (raw)
            f32x4 sc[4];
#pragma unroll
            for (int t = 0; t < 4; t++) sc[t] = (f32x4){0.f, 0.f, 0.f, 0.f};
#pragma unroll
            for (int t = 0; t < 4; t++) {
                sc[t] = __builtin_amdgcn_mfma_f32_16x16x32_bf16(kc0[t], qf0, sc[t], 0, 0, 0);
                sc[t] = __builtin_amdgcn_mfma_f32_16x16x32_bf16(kc1[t], qf1, sc[t], 0, 0, 0);
            }

            bf16x8 vv0[4], vv1[4];
#pragma unroll
            for (int t = 0; t < 4; t++) {
                vv0[t] = lds_read_swz(Vs[cb], t * 16 + c15, quad);
                vv1[t] = lds_read_swz(Vs[cb], t * 16 + c15, 4 + quad);
            }

            if (jt == it) {
                const int gi = i0 + w * 16 + c15;
#pragma unroll
                for (int t = 0; t < 4; t++) {
#pragma unroll
                    for (int r = 0; r < 4; r++) {
                        int gj = j0 + t * 16 + quad * 4 + r;
                        if (gj > gi) sc[t][r] = -1e30f;
                    }
                }
            }

            // row-max: in-register tree over 16 j-values + 2 cross-quad shuffles
            float x0 = fmaxf(fmaxf(sc[0][0], sc[0][1]), fmaxf(sc[0][2], sc[0][3]));
            float x1 = fmaxf(fmaxf(sc[1][0], sc[1][1]), fmaxf(sc[1][2], sc[1][3]));
            float x2 = fmaxf(fmaxf(sc[2][0], sc[2][1]), fmaxf(sc[2][2], sc[2][3]));
            float x3 = fmaxf(fmaxf(sc[3][0], sc[3][1]), fmaxf(sc[3][2], sc[3][3]));
            float tm = fmaxf(fmaxf(x0, x1), fmaxf(x2, x3));
            tm = fmaxf(tm, __shfl_xor(tm, 16));
            tm = fmaxf(tm, __shfl_xor(tm, 32));

            // defer-max: skip rescale unless max grew by > 64 raw (8 scaled)
            if (!__all(tm <= m_st + 64.0f)) {
                float mnew = fmaxf(m_st, tm);
                float alpha = __expf((m_st - mnew) * C);
                l_st *= alpha;
#pragma unroll
                for (int t = 0; t < 4; t++)
#pragma unroll
                    for (int r = 0; r < 4; r++) Oc[t][r] *= alpha;
                m_st = mnew;
            }

            const float mC = m_st * C;
            float p[4][4];
#pragma unroll
            for (int t = 0; t < 4; t++)
#pragma unroll
                for (int r = 0; r < 4; r++)
                    p[t][r] = __expf(__builtin_fmaf(sc[t][r], C, -mC));

            // partial row-sum (this quad's 16 j's); butterfly deferred to epilogue
            float s0 = (p[0][0] + p[0][1]) + (p[0][2] + p[0][3]);
            float s1 = (p[1][0] + p[1][1]) + (p[1][2] + p[1][3]);
            float s2 = (p[2][0] + p[2][1]) + (p[2][2] + p[2][3]);
            float s3 = (p[3][0] + p[3][1]) + (p[3][2] + p[3][3]);
            l_st += (s0 + s1) + (s2 + s3);

            // P[q][j] -> wave-private LDS, packed b32 pairs
#pragma unroll
            for (int t = 0; t < 4; t++) {
#pragma unroll
                for (int hh = 0; hh < 2; hh++) {
                    unsigned int pk = (unsigned int)f2bf(p[t][2 * hh])
                                    | ((unsigned int)f2bf(p[t][2 * hh + 1]) << 16);
                    *reinterpret_cast<unsigned int*>(
                        &Pl[w * 16 + c15][t * 16 + quad * 4 + 2 * hh]) = pk;
                }
            }

            bf16x8 ap0 = *reinterpret_cast<const bf16x8*>(&Pl[w * 16 + c15][quad * 8]);
            bf16x8 ap1 = *reinterpret_cast<const bf16x8*>(&Pl[w * 16 + c15][32 + quad * 8]);
#pragma unroll
            for (int t = 0; t < 4; t++) {
                Oc[t] = __builtin_amdgcn_mfma_f32_16x16x32_bf16(vv0[t], ap0, Oc[t], 0, 0, 0);
                Oc[t] = __builtin_amdgcn_mfma_f32_16x16x32_bf16(vv1[t], ap1, Oc[t], 0, 0, 0);
            }
        }

        // epilogue: finish l across quads, normalize, stage, coalesced store
        l_st += __shfl_xor(l_st, 16);
        l_st += __shfl_xor(l_st, 32);
        float inv = 1.0f / l_st;
#pragma unroll
        for (int t = 0; t < 4; t++) {
#pragma unroll
            for (int hh = 0; hh < 2; hh++) {
                unsigned int pk = (unsigned int)f2bf(Oc[t][2 * hh] * inv)
                                | ((unsigned int)f2bf(Oc[t][2 * hh + 1] * inv) << 16);
                *reinterpret_cast<unsigned int*>(
                    &Pl[w * 16 + c15][t * 16 + quad * 4 + 2 * hh]) = pk;
            }
        }
        {
            int row = lane >> 2;
            int ch = lane & 3;
            int gi = i0 + w * 16 + row;
            size_t ob = ((size_t)b * SEQ + gi) * 1024 + h * 64 + ch * 16;
            uint4 v0 = *reinterpret_cast<const uint4*>(&Pl[w * 16 + row][ch * 16]);
            uint4 v1 = *reinterpret_cast<const uint4*>(&Pl[w * 16 + row][ch * 16 + 8]);
            *reinterpret_cast<uint4*>(&ab[ob]) = v0;
            *reinterpret_cast<uint4*>(&ab[ob + 8]) = v1;
        }
    }
}

// MFMA NT-GEMM: out[m,n] = sum_i ab[m,i] * Wo[n,i]; bf16 in, fp32 out.
// 64x128 tile (512 blocks -> 2/CU) to fix the 1-block/CU occupancy hole.
__global__ __launch_bounds__(256) void out_mfma_kernel(
    const unsigned short* __restrict__ A, const unsigned short* __restrict__ Wob,
    float* __restrict__ out)
{
    const int lin = blockIdx.x;
    const int b = lin & 7;
    const int y = lin >> 3;       // 0..63
    const int m0 = y * 64;
    const int n0g = b * 128;

    __shared__ __align__(16) unsigned short As[2][64][64];    // 16 KB
    __shared__ __align__(16) unsigned short Bs[2][128][64];   // 32 KB

    const int tid = threadIdx.x;
    const int w = tid >> 6;
    const int lane = tid & 63;
    const int quad = lane >> 4;
    const int c15 = lane & 15;
    const int qm = w >> 1, qn = w & 1;   // wave owns 32x64 of the 64x128 tile
    const int srow8 = lane >> 3;
    const int sch = lane & 7;

    auto stage = [&](int k0, int buf) {
#pragma unroll
        for (int i = 0; i < 2; i++) {
            const int row = w * 16 + i * 8 + srow8;
            const int ch = sch ^ (row & 7);
            gload_lds16(A + (size_t)(m0 + row) * 1024 + k0 + ch * 8,
                        &As[buf][w * 16 + i * 8][0]);
        }
#pragma unroll
        for (int i = 0; i < 4; i++) {
            const int row = i * 32 + w * 8 + srow8;
            const int ch = sch ^ (row & 7);
            gload_lds16(Wob + (size_t)(n0g + row) * 1024 + k0 + ch * 8,
                        &Bs[buf][i * 32 + w * 8][0]);
        }
    };

    f32x4 acc[2][4];
#pragma unroll
    for (int mi = 0; mi < 2; mi++)
#pragma unroll
        for (int ni = 0; ni < 4; ni++) acc[mi][ni] = (f32x4){0.f, 0.f, 0.f, 0.f};

    stage(0, 0);
    for (int k0 = 0; k0 < 1024; k0 += 64) {
        const int cb = (k0 >> 6) & 1;
        __syncthreads();
        if (k0 < 960) stage(k0 + 64, cb ^ 1);

        bf16x8 af[2][2], bfr[2][4];
#pragma unroll
        for (int ks = 0; ks < 2; ks++) {
#pragma unroll
            for (int mi = 0; mi < 2; mi++)
                af[ks][mi] = lds_read_swz(As[cb], qm * 32 + mi * 16 + c15, ks * 4 + quad);
#pragma unroll
            for (int ni = 0; ni < 4; ni++)
                bfr[ks][ni] = lds_read_swz(Bs[cb], qn * 64 + ni * 16 + c15, ks * 4 + quad);
        }
#pragma unroll
        for (int ks = 0; ks < 2; ks++)
#pragma unroll
            for (int mi = 0; mi < 2; mi++)
#pragma unroll
                for (int ni = 0; ni < 4; ni++)
                    acc[mi][ni] = __builtin_amdgcn_mfma_f32_16x16x32_bf16(af[ks][mi], bfr[ks][ni], acc[mi][ni], 0, 0, 0);
    }

#pragma unroll
    for (int mi = 0; mi < 2; mi++) {
#pragma unroll
        for (int r = 0; r < 4; r++) {
            int m = m0 + qm * 32 + mi * 16 + quad * 4 + r;
#pragma unroll
            for (int ni = 0; ni < 4; ni++) {
                int n = n0g + qn * 64 + ni * 16 + c15;
                out[(size_t)m * 1024 + n] = acc[mi][ni][r];
            }
        }
    }
}

extern "C" void kernel_launch(void* const* d_in, const int* in_sizes, int n_in,
                              void* d_out, int out_size, void* d_ws, size_t ws_size,
                              hipStream_t stream)
{
    const float* x  = (const float*)d_in[0];
    const float* Wq = (const float*)d_in[1];
    const float* Wk = (const float*)d_in[2];
    const float* Wv = (const float*)d_in[3];
    const float* Wo = (const float*)d_in[4];
    float* out = (float*)d_out;

    const size_t QKV_ELEMS = (size_t)BATCH * SEQ * D_MODEL;  // 4194304

    unsigned short* qb = (unsigned short*)d_ws;
    unsigned short* kb = qb + QKV_ELEMS;
    unsigned short* vt = kb + QKV_ELEMS;   // [b][h][d][s]
    unsigned short* ab = vt + QKV_ELEMS;
    unsigned short* w3bf = ab;             // dead during qkv
    unsigned short* wobf = qb;             // dead during out
    unsigned short* xbuf = (unsigned short*)d_out;               // first 8MB of out
    float2* tab = (float2*)((char*)d_out + 8 * 1024 * 1024);     // 512 KB after xbuf

    // x + Wq/Wk/Wv conversion + RoPE table: 1835008 + 65536 threads
    conv4_kernel<<<dim3(7424), 256, 0, stream>>>(x, Wq, Wk, Wv, xbuf, w3bf, tab);
    qkv_mfma_kernel<<<dim3(768), 256, 0, stream>>>(xbuf, w3bf, tab, qb, kb, vt);
    attn_kernel<<<dim3(16, 32), 256, 0, stream>>>(qb, kb, vt, ab);
    conv_kernel<<<dim3(1024), 256, 0, stream>>>(Wo, wobf, 262144);
    out_mfma_kernel<<<dim3(512), 256, 0, stream>>>(ab, wobf, out);
}

// Round 6
// 205.229 us; speedup vs baseline: 1.4128x; 1.0512x over previous
//
#include <hip/hip_runtime.h>

#define D_MODEL 1024
#define NUM_HEADS 16
#define SEQ 2048
#define BATCH 2

typedef __attribute__((ext_vector_type(8))) short bf16x8;
typedef __attribute__((ext_vector_type(4))) float f32x4;

__device__ __forceinline__ float bf2f(unsigned short u) {
    return __uint_as_float(((unsigned int)u) << 16);
}
__device__ __forceinline__ unsigned short f2bf(float f) {
    unsigned int u = __float_as_uint(f);
    return (unsigned short)((u + 0x7FFFu + ((u >> 16) & 1u)) >> 16);   // RTNE
}
__device__ __forceinline__ ushort4 pack4(float4 v) {
    return make_ushort4(f2bf(v.x), f2bf(v.y), f2bf(v.z), f2bf(v.w));
}

// async global->LDS, 16B per lane. LDS dest = wave-uniform base + lane*16.
__device__ __forceinline__ void gload_lds16(const unsigned short* g, unsigned short* l) {
    __builtin_amdgcn_global_load_lds(
        (const __attribute__((address_space(1))) unsigned int*)g,
        (__attribute__((address_space(3))) unsigned int*)l,
        16, 0, 0);
}

// Swizzled 16B read from a [N][64] bf16 LDS tile (128B rows, 8 chunks).
// LDS[row][chunk] holds G[row][chunk ^ (row&7)]; reading chunk^(row&7)
// recovers the logical element and is conflict-free across 16 rows.
__device__ __forceinline__ bf16x8 lds_read_swz(const unsigned short (*tile)[64], int row, int chunk) {
    const char* p = reinterpret_cast<const char*>(tile);
    return *reinterpret_cast<const bf16x8*>(p + row * 128 + (((chunk ^ (row & 7))) << 4));
}

// Same pattern for 64B rows (BK=32 tiles, 4 chunks, XOR row&3).
__device__ __forceinline__ bf16x8 lds_read_swz32(const unsigned short (*tile)[32], int row, int chunk) {
    const char* p = reinterpret_cast<const char*>(tile);
    return *reinterpret_cast<const bf16x8*>(p + row * 64 + (((chunk ^ (row & 3))) << 4));
}

// fp32 -> bf16 bulk convert (one float4 -> ushort4 per thread).
__global__ __launch_bounds__(256) void conv_kernel(
    const float* __restrict__ src, unsigned short* __restrict__ dst, int n4)
{
    int i = blockIdx.x * 256 + threadIdx.x;
    if (i < n4) {
        float4 v = reinterpret_cast<const float4*>(src)[i];
        reinterpret_cast<ushort4*>(dst)[i] = pack4(v);
    }
}

// Fused conversion of x (1048576 float4) + Wq/Wk/Wv (262144 float4 each)
// + RoPE cos/sin table build (2048 x 32 float2).
__global__ __launch_bounds__(256) void conv4_kernel(
    const float* __restrict__ x, const float* __restrict__ Wq,
    const float* __restrict__ Wk, const float* __restrict__ Wv,
    unsigned short* __restrict__ xb, unsigned short* __restrict__ w3bf,
    float2* __restrict__ tab)
{
    int i = blockIdx.x * 256 + threadIdx.x;
    if (i < 1835008) {
        const float* src;
        unsigned short* dst;
        int off;
        if (i < 1048576) {
            src = x; dst = xb; off = i;
        } else {
            int j = i - 1048576;
            int which = j >> 18;            // 262144 = 2^18
            off = j & 0x3FFFF;
            src = (which == 0) ? Wq : (which == 1) ? Wk : Wv;
            dst = w3bf + ((size_t)which << 20);   // 1048576 ushorts per W
        }
        float4 v = reinterpret_cast<const float4*>(src)[off];
        reinterpret_cast<ushort4*>(dst)[off] = pack4(v);
    } else {
        int idx = i - 1835008;              // 65536 entries
        int s = idx >> 5, d2 = idx & 31;
        float inv = powf(10000.0f, -(float)d2 / 32.0f);
        float sn, cs;
        sincosf((float)s * inv, &sn, &cs);
        tab[idx] = make_float2(cs, sn);
    }
}

// MFMA NT-GEMM: C[m,n] = sum_i xb[m,i] * W[n,i], all bf16.
// 128x128 tile, BK=32, 32KB LDS double-buffer (m97-proven config: ~5
// blocks/CU so cross-block wave overlap hides the barrier drain).
// Q,K: RoPE fused (table-based), [b][h][s][d]. V: TRANSPOSED [b][h][d][s].
__global__ __launch_bounds__(256) void qkv_mfma_kernel(
    const unsigned short* __restrict__ xb,   // [4096][1024] bf16
    const unsigned short* __restrict__ w3,   // [3][1024][1024] bf16
    const float2* __restrict__ tab,          // [2048][32] cos,sin
    unsigned short* __restrict__ qb, unsigned short* __restrict__ kb,
    unsigned short* __restrict__ vt)
{
    const int lin = blockIdx.x;
    const int b = lin & 7;
    const int t = lin >> 3;
    const int which = t % 3;
    const int y = t / 3;
    const unsigned short* __restrict__ W = w3 + (size_t)which * 1048576;
    const int m0 = y * 128;
    const int n0g = b * 128;

    __shared__ __align__(16) unsigned short As[2][128][32];  // 16 KB
    __shared__ __align__(16) unsigned short Bs[2][128][32];  // 16 KB

    const int tid = threadIdx.x;
    const int w = tid >> 6;
    const int lane = tid & 63;
    const int quad = lane >> 4;
    const int c15 = lane & 15;
    const int qm = w >> 1, qn = w & 1;
    const int srow4 = lane >> 2;   // row within a 16-row staging instruction
    const int sch4 = lane & 3;     // 16B chunk within a 64B row

    // Stage one BK=32 K-slab of A and B into buffer buf.
    // 2 calls x 4 waves x 16 rows = 128 rows of 64B each.
    auto stage = [&](int k0, int buf) {
#pragma unroll
        for (int i = 0; i < 2; i++) {
            const int row = i * 64 + w * 16 + srow4;
            const int ch = sch4 ^ (row & 3);
            gload_lds16(xb + (size_t)(m0 + row) * 1024 + k0 + ch * 8,
                        &As[buf][i * 64 + w * 16][0]);
            gload_lds16(W + (size_t)(n0g + row) * 1024 + k0 + ch * 8,
                        &Bs[buf][i * 64 + w * 16][0]);
        }
    };

    f32x4 acc[4][4];
#pragma unroll
    for (int mi = 0; mi < 4; mi++)
#pragma unroll
        for (int ni = 0; ni < 4; ni++) acc[mi][ni] = (f32x4){0.f, 0.f, 0.f, 0.f};

    stage(0, 0);
    for (int k0 = 0; k0 < 1024; k0 += 32) {
        const int cb = (k0 >> 5) & 1;
        __syncthreads();                       // staging of cb complete
        if (k0 < 992) stage(k0 + 32, cb ^ 1);  // prefetch; drains at next barrier

        bf16x8 af[4], bfr[4];
#pragma unroll
        for (int mi = 0; mi < 4; mi++)
            af[mi] = lds_read_swz32(As[cb], qm * 64 + mi * 16 + c15, quad);
#pragma unroll
        for (int ni = 0; ni < 4; ni++)
            bfr[ni] = lds_read_swz32(Bs[cb], qn * 64 + ni * 16 + c15, quad);
#pragma unroll
        for (int mi = 0; mi < 4; mi++)
#pragma unroll
            for (int ni = 0; ni < 4; ni++)
                acc[mi][ni] = __builtin_amdgcn_mfma_f32_16x16x32_bf16(af[mi], bfr[ni], acc[mi][ni], 0, 0, 0);
    }

    // Epilogue: RoPE (Q,K) via cos/sin table -> wave-private LDS stage ->
    // coalesced stores. Wave's n-range = one head: h = b*2 + qn.
    __syncthreads();
    unsigned short* stg = &As[0][0][0] + w * (16 * 72);   // 16 rows x 72 stride, per wave
    const int hq = b * 2 + qn;
    unsigned short* outp = (which == 0) ? qb : kb;
    const int odd = c15 & 1;

#pragma unroll
    for (int mi = 0; mi < 4; mi++) {
#pragma unroll
        for (int r = 0; r < 4; r++) {
            int m = m0 + qm * 64 + mi * 16 + quad * 4 + r;
            int s = m & (SEQ - 1);
            const float2* trow = tab + (s << 5);
#pragma unroll
            for (int ni = 0; ni < 4; ni++) {
                float val = acc[mi][ni][r];
                float res;
                if (which < 2) {
                    float part = __shfl_xor(val, 1);
                    float2 cs = trow[(ni * 16 + c15) >> 1];
                    res = odd ? (part * cs.y + val * cs.x) : (val * cs.x - part * cs.y);
                } else {
                    res = val;
                }
                stg[(quad * 4 + r) * 72 + ni * 16 + c15] = f2bf(res);
            }
        }
        if (which < 2) {
            int row = lane >> 2;
            int ch = lane & 3;
            int m = m0 + qm * 64 + mi * 16 + row;
            int s = m & (SEQ - 1);
            int bb = m >> 11;
            size_t ob = (((size_t)bb * NUM_HEADS + hq) * SEQ + s) * 64 + ch * 16;
            uint4 v0 = *reinterpret_cast<const uint4*>(&stg[row * 72 + ch * 16]);
            uint4 v1 = *reinterpret_cast<const uint4*>(&stg[row * 72 + ch * 16 + 8]);
            *reinterpret_cast<uint4*>(&outp[ob]) = v0;
            *reinterpret_cast<uint4*>(&outp[ob + 8]) = v1;
        } else {
            int mbase = m0 + qm * 64 + mi * 16;
            int bb = mbase >> 11;
            int s_base = mbase & (SEQ - 1);
            unsigned short tmp[16];
#pragma unroll
            for (int sl = 0; sl < 16; sl++) tmp[sl] = stg[sl * 72 + lane];
            size_t ob = (((size_t)bb * NUM_HEADS + hq) * 64 + lane) * SEQ + s_base;
            *reinterpret_cast<uint4*>(&vt[ob])     = *reinterpret_cast<uint4*>(&tmp[0]);
            *reinterpret_cast<uint4*>(&vt[ob + 8]) = *reinterpret_cast<uint4*>(&tmp[8]);
        }
    }
}

// MFMA flash attention with SWAPPED-operand softmax.
// S^T = mfma(K, Q): lane's c15 = its q-row; row-max is an in-register tree
// + 2 cross-quad shuffles; row-sum butterfly defers to the epilogue. PV is
// swapped too (O^T = mfma(V^T, P)), so m/l/alpha are lane-local scalars.
// Defer-max (THR=64 raw) skips the O-rescale on almost every iteration.
__global__ __launch_bounds__(256) void attn_kernel(
    const unsigned short* __restrict__ qb, const unsigned short* __restrict__ kb,
    const unsigned short* __restrict__ vt, unsigned short* __restrict__ ab)
{
    const int xpair = blockIdx.x;   // 0..15
    const int bh = blockIdx.y;
    const int b = bh >> 4, h = bh & 15;
    const size_t base = (size_t)bh * SEQ * 64;     // qb/kb [b][h][s][d]
    const size_t vbase = (size_t)bh * 64 * SEQ;    // vt [b][h][d][s]
    const int tid = threadIdx.x;
    const int w = tid >> 6;
    const int lane = tid & 63;
    const int quad = lane >> 4;
    const int c15 = lane & 15;
    const int srow8 = lane >> 3;
    const int sch = lane & 7;
    const float C = 0.125f;   // softmax scale 1/sqrt(64)

    __shared__ __align__(16) unsigned short Ks[2][64][64];   // [buf][j][d]
    __shared__ __align__(16) unsigned short Vs[2][64][64];   // [buf][d][j]
    __shared__ __align__(16) unsigned short Pl[64][72];      // wave-private rows

    auto stage = [&](int jts, int buf) {
        const int j0s = jts * 64;
#pragma unroll
        for (int i = 0; i < 2; i++) {
            const int row = w * 16 + i * 8 + srow8;
            const int ch = sch ^ (row & 7);
            gload_lds16(kb + base + (size_t)(j0s + row) * 64 + ch * 8,
                        &Ks[buf][w * 16 + i * 8][0]);
            gload_lds16(vt + vbase + (size_t)row * SEQ + j0s + ch * 8,
                        &Vs[buf][w * 16 + i * 8][0]);
        }
    };

    for (int pass = 0; pass < 2; pass++) {
        const int it = pass ? xpair : (31 - xpair);   // heavy tile first
        const int i0 = it * 64;

        const int qrow = i0 + w * 16 + c15;
        bf16x8 qf0 = *reinterpret_cast<const bf16x8*>(&qb[base + (size_t)qrow * 64 + quad * 8]);
        bf16x8 qf1 = *reinterpret_cast<const bf16x8*>(&qb[base + (size_t)qrow * 64 + 32 + quad * 8]);

        float m_st = -1e30f, l_st = 0.f;    // lane-local: q-row = c15
        f32x4 Oc[4];                        // Oc[t][r]: d = t*16+quad*4+r, q = c15
#pragma unroll
        for (int t = 0; t < 4; t++) Oc[t] = (f32x4){0.f, 0.f, 0.f, 0.f};

        __syncthreads();          // prev pass done reading buffers
        stage(0, 0);              // prologue: tile 0 -> buf 0

        for (int jt = 0; jt <= it; jt++) {
            const int j0 = jt * 64;
            const int cb = jt & 1;

            __syncthreads();      // staging for cb complete; nb free to overwrite
            if (jt < it) stage(jt + 1, cb ^ 1);

            bf16x8 kc0[4], kc1[4];
#pragma unroll
            for (int t = 0; t < 4; t++) {
                kc0[t] = lds_read_swz(Ks[cb], t * 16 + c15, quad);
                kc1[t] = lds_read_swz(Ks[cb], t * 16 + c15, 4 + quad);
            }

            // S^T[j][q]: sc[t][r] = S[j = j0+t*16+quad*4+r][q-row = c15] (raw)
            f32x4 sc[4];
#pragma unroll
            for (int t = 0; t < 4; t++) sc[t] = (f32x4){0.f, 0.f, 0.f, 0.f};
#pragma unroll
            for (int t = 0; t < 4; t++) {
                sc[t] = __builtin_amdgcn_mfma_f32_16x16x32_bf16(kc0[t], qf0, sc[t], 0, 0, 0);
                sc[t] = __builtin_amdgcn_mfma_f32_16x16x32_bf16(kc1[t], qf1, sc[t], 0, 0, 0);
            }

            bf16x8 vv0[4], vv1[4];
#pragma unroll
            for (int t = 0; t < 4; t++) {
                vv0[t] = lds_read_swz(Vs[cb], t * 16 + c15, quad);
                vv1[t] = lds_read_swz(Vs[cb], t * 16 + c15, 4 + quad);
            }

            if (jt == it) {
                const int gi = i0 + w * 16 + c15;
#pragma unroll
                for (int t = 0; t < 4; t++) {
#pragma unroll
                    for (int r = 0; r < 4; r++) {
                        int gj = j0 + t * 16 + quad * 4 + r;
                        if (gj > gi) sc[t][r] = -1e30f;
                    }
                }
            }

            // row-max: in-register tree over 16 j-values + 2 cross-quad shuffles
            float x0 = fmaxf(fmaxf(sc[0][0], sc[0][1]), fmaxf(sc[0][2], sc[0][3]));
            float x1 = fmaxf(fmaxf(sc[1][0], sc[1][1]), fmaxf(sc[1][2], sc[1][3]));
            float x2 = fmaxf(fmaxf(sc[2][0], sc[2][1]), fmaxf(sc[2][2], sc[2][3]));
            float x3 = fmaxf(fmaxf(sc[3][0], sc[3][1]), fmaxf(sc[3][2], sc[3][3]));
            float tm = fmaxf(fmaxf(x0, x1), fmaxf(x2, x3));
            tm = fmaxf(tm, __shfl_xor(tm, 16));
            tm = fmaxf(tm, __shfl_xor(tm, 32));

            // defer-max: skip rescale unless max grew by > 64 raw (8 scaled)
            if (!__all(tm <= m_st + 64.0f)) {
                float mnew = fmaxf(m_st, tm);
                float alpha = __expf((m_st - mnew) * C);
                l_st *= alpha;
#pragma unroll
                for (int t = 0; t < 4; t++)
#pragma unroll
                    for (int r = 0; r < 4; r++) Oc[t][r] *= alpha;
                m_st = mnew;
            }

            const float mC = m_st * C;
            float p[4][4];
#pragma unroll
            for (int t = 0; t < 4; t++)
#pragma unroll
                for (int r = 0; r < 4; r++)
                    p[t][r] = __expf(__builtin_fmaf(sc[t][r], C, -mC));

            // partial row-sum (this quad's 16 j's); butterfly deferred to epilogue
            float s0 = (p[0][0] + p[0][1]) + (p[0][2] + p[0][3]);
            float s1 = (p[1][0] + p[1][1]) + (p[1][2] + p[1][3]);
            float s2 = (p[2][0] + p[2][1]) + (p[2][2] + p[2][3]);
            float s3 = (p[3][0] + p[3][1]) + (p[3][2] + p[3][3]);
            l_st += (s0 + s1) + (s2 + s3);

            // P[q][j] -> wave-private LDS, packed b32 pairs
#pragma unroll
            for (int t = 0; t < 4; t++) {
#pragma unroll
                for (int hh = 0; hh < 2; hh++) {
                    unsigned int pk = (unsigned int)f2bf(p[t][2 * hh])
                                    | ((unsigned int)f2bf(p[t][2 * hh + 1]) << 16);
                    *reinterpret_cast<unsigned int*>(
                        &Pl[w * 16 + c15][t * 16 + quad * 4 + 2 * hh]) = pk;
                }
            }

            bf16x8 ap0 = *reinterpret_cast<const bf16x8*>(&Pl[w * 16 + c15][quad * 8]);
            bf16x8 ap1 = *reinterpret_cast<const bf16x8*>(&Pl[w * 16 + c15][32 + quad * 8]);
#pragma unroll
            for (int t = 0; t < 4; t++) {
                Oc[t] = __builtin_amdgcn_mfma_f32_16x16x32_bf16(vv0[t], ap0, Oc[t], 0, 0, 0);
                Oc[t] = __builtin_amdgcn_mfma_f32_16x16x32_bf16(vv1[t], ap1, Oc[t], 0, 0, 0);
            }
        }

        // epilogue: finish l across quads, normalize, stage, coalesced store
        l_st += __shfl_xor(l_st, 16);
        l_st += __shfl_xor(l_st, 32);
        float inv = 1.0f / l_st;
#pragma unroll
        for (int t = 0; t < 4; t++) {
#pragma unroll
            for (int hh = 0; hh < 2; hh++) {
                unsigned int pk = (unsigned int)f2bf(Oc[t][2 * hh] * inv)
                                | ((unsigned int)f2bf(Oc[t][2 * hh + 1] * inv) << 16);
                *reinterpret_cast<unsigned int*>(
                    &Pl[w * 16 + c15][t * 16 + quad * 4 + 2 * hh]) = pk;
            }
        }
        {
            int row = lane >> 2;
            int ch = lane & 3;
            int gi = i0 + w * 16 + row;
            size_t ob = ((size_t)b * SEQ + gi) * 1024 + h * 64 + ch * 16;
            uint4 v0 = *reinterpret_cast<const uint4*>(&Pl[w * 16 + row][ch * 16]);
            uint4 v1 = *reinterpret_cast<const uint4*>(&Pl[w * 16 + row][ch * 16 + 8]);
            *reinterpret_cast<uint4*>(&ab[ob]) = v0;
            *reinterpret_cast<uint4*>(&ab[ob + 8]) = v1;
        }
    }
}

// MFMA NT-GEMM: out[m,n] = sum_i ab[m,i] * Wo[n,i]; bf16 in, fp32 out.
// 64x128 tile, BK=32 (24KB LDS -> 6 blocks/CU).
__global__ __launch_bounds__(256) void out_mfma_kernel(
    const unsigned short* __restrict__ A, const unsigned short* __restrict__ Wob,
    float* __restrict__ out)
{
    const int lin = blockIdx.x;
    const int b = lin & 7;
    const int y = lin >> 3;       // 0..63
    const int m0 = y * 64;
    const int n0g = b * 128;

    __shared__ __align__(16) unsigned short As[2][64][32];    // 8 KB
    __shared__ __align__(16) unsigned short Bs[2][128][32];   // 16 KB

    const int tid = threadIdx.x;
    const int w = tid >> 6;
    const int lane = tid & 63;
    const int quad = lane >> 4;
    const int c15 = lane & 15;
    const int qm = w >> 1, qn = w & 1;   // wave owns 32x64 of the 64x128 tile
    const int srow4 = lane >> 2;
    const int sch4 = lane & 3;

    auto stage = [&](int k0, int buf) {
        {
            const int row = w * 16 + srow4;
            const int ch = sch4 ^ (row & 3);
            gload_lds16(A + (size_t)(m0 + row) * 1024 + k0 + ch * 8,
                        &As[buf][w * 16][0]);
        }
#pragma unroll
        for (int i = 0; i < 2; i++) {
            const int row = i * 64 + w * 16 + srow4;
            const int ch = sch4 ^ (row & 3);
            gload_lds16(Wob + (size_t)(n0g + row) * 1024 + k0 + ch * 8,
                        &Bs[buf][i * 64 + w * 16][0]);
        }
    };

    f32x4 acc[2][4];
#pragma unroll
    for (int mi = 0; mi < 2; mi++)
#pragma unroll
        for (int ni = 0; ni < 4; ni++) acc[mi][ni] = (f32x4){0.f, 0.f, 0.f, 0.f};

    stage(0, 0);
    for (int k0 = 0; k0 < 1024; k0 += 32) {
        const int cb = (k0 >> 5) & 1;
        __syncthreads();
        if (k0 < 992) stage(k0 + 32, cb ^ 1);

        bf16x8 af[2], bfr[4];
#pragma unroll
        for (int mi = 0; mi < 2; mi++)
            af[mi] = lds_read_swz32(As[cb], qm * 32 + mi * 16 + c15, quad);
#pragma unroll
        for (int ni = 0; ni < 4; ni++)
            bfr[ni] = lds_read_swz32(Bs[cb], qn * 64 + ni * 16 + c15, quad);
#pragma unroll
        for (int mi = 0; mi < 2; mi++)
#pragma unroll
            for (int ni = 0; ni < 4; ni++)
                acc[mi][ni] = __builtin_amdgcn_mfma_f32_16x16x32_bf16(af[mi], bfr[ni], acc[mi][ni], 0, 0, 0);
    }

#pragma unroll
    for (int mi = 0; mi < 2; mi++) {
#pragma unroll
        for (int r = 0; r < 4; r++) {
            int m = m0 + qm * 32 + mi * 16 + quad * 4 + r;
#pragma unroll
            for (int ni = 0; ni < 4; ni++) {
                int n = n0g + qn * 64 + ni * 16 + c15;
                out[(size_t)m * 1024 + n] = acc[mi][ni][r];
            }
        }
    }
}

extern "C" void kernel_launch(void* const* d_in, const int* in_sizes, int n_in,
                              void* d_out, int out_size, void* d_ws, size_t ws_size,
                              hipStream_t stream)
{
    const float* x  = (const float*)d_in[0];
    const float* Wq = (const float*)d_in[1];
    const float* Wk = (const float*)d_in[2];
    const float* Wv = (const float*)d_in[3];
    const float* Wo = (const float*)d_in[4];
    float* out = (float*)d_out;

    const size_t QKV_ELEMS = (size_t)BATCH * SEQ * D_MODEL;  // 4194304

    unsigned short* qb = (unsigned short*)d_ws;
    unsigned short* kb = qb + QKV_ELEMS;
    unsigned short* vt = kb + QKV_ELEMS;   // [b][h][d][s]
    unsigned short* ab = vt + QKV_ELEMS;
    unsigned short* w3bf = ab;             // dead during qkv
    unsigned short* wobf = qb;             // dead during out
    unsigned short* xbuf = (unsigned short*)d_out;               // first 8MB of out
    float2* tab = (float2*)((char*)d_out + 8 * 1024 * 1024);     // 512 KB after xbuf

    // x + Wq/Wk/Wv conversion + RoPE table: 1835008 + 65536 threads
    conv4_kernel<<<dim3(7424), 256, 0, stream>>>(x, Wq, Wk, Wv, xbuf, w3bf, tab);
    qkv_mfma_kernel<<<dim3(768), 256, 0, stream>>>(xbuf, w3bf, tab, qb, kb, vt);
    attn_kernel<<<dim3(16, 32), 256, 0, stream>>>(qb, kb, vt, ab);
    conv_kernel<<<dim3(1024), 256, 0, stream>>>(Wo, wobf, 262144);
    out_mfma_kernel<<<dim3(512), 256, 0, stream>>>(ab, wobf, out);
}